// Round 12
// baseline (1949.734 us; speedup 1.0000x reference)
//
#include <hip/hip_runtime.h>

// ---------------------------------------------------------------------------
// ErnieLayout encoder, 12 layers, B=2 S=2048 D=768 H=12 DH=64, bf16 MFMA.
// r12: attn V-operands in registers (issued early, T14) — LDS 24KB, staging
// halved; gemm_core 2-phase prefetch (stage t+1 before compute t, 1 barrier
// per K-step, double-buffered LDS). fp8 bias acc-init, ones-MFMA, defer-max.
// ---------------------------------------------------------------------------

#define BB 2
#define SS 2048
#define DD 768
#define HH 12
#define NLAYER 12
#define MM 4096  // BB*SS

typedef unsigned short u16;
typedef unsigned char u8;
typedef __attribute__((ext_vector_type(8))) short bf16x8;
typedef __attribute__((ext_vector_type(4))) float f32x4;
typedef __attribute__((ext_vector_type(2))) float f32x2;

#define LOG2E 1.44269504088896340736f
#define WT_LSTRIDE 2359296  // per-layer u16 elements in wtb (4*768*768)

__device__ __forceinline__ u16 f2bf(float f) {
  unsigned u = __float_as_uint(f);
  unsigned r = (u + 0x7FFFu + ((u >> 16) & 1u)) >> 16;
  return (u16)r;
}
__device__ __forceinline__ float bf2f(unsigned u) {
  return __uint_as_float(u << 16);
}
__device__ __forceinline__ unsigned cvtpk(float a, float b) {
  unsigned r;
  asm("v_cvt_pk_bf16_f32 %0, %1, %2" : "=v"(r) : "v"(a), "v"(b));
  return r;
}
__device__ __forceinline__ float exp2v(float x) {
  float r;
  asm("v_exp_f32 %0, %1" : "=v"(r) : "v"(x));
  return r;
}
__device__ __forceinline__ float log2v(float x) {
  float r;
  asm("v_log_f32 %0, %1" : "=v"(r) : "v"(x));
  return r;
}
__device__ __forceinline__ float max3f(float a, float b, float c) {
  float r;
  asm("v_max3_f32 %0, %1, %2, %3" : "=v"(r) : "v"(a), "v"(b), "v"(c));
  return r;
}

__device__ __forceinline__ void g2lds16(const void* g, void* l) {
  __builtin_amdgcn_global_load_lds(
      (const __attribute__((address_space(1))) unsigned int*)g,
      (__attribute__((address_space(3))) unsigned int*)l, 16, 0, 0);
}

// --------------------------------------------------------------------------
// hidden fp32 -> bf16
__global__ __launch_bounds__(256) void k_hb(const float4* __restrict__ x,
                                            uint2* __restrict__ o, int n4) {
  int i = blockIdx.x * 256 + threadIdx.x;
  if (i < n4) {
    float4 v = x[i];
    uint2 r;
    r.x = (unsigned)f2bf(v.x) | ((unsigned)f2bf(v.y) << 16);
    r.y = (unsigned)f2bf(v.z) | ((unsigned)f2bf(v.w) << 16);
    o[i] = r;
  }
}

// --------------------------------------------------------------------------
// relative-position bucketing; hardware log2 (exact algebraic rewrite)
__device__ __forceinline__ int bucket1(int rel) {
  int ret = rel > 0 ? 16 : 0;
  int n = rel < 0 ? -rel : rel;
  if (n < 8) return ret + n;
  int v = 8 + (int)(log2v((float)n * 0.125f) * 2.0f);
  return ret + (v < 15 ? v : 15);
}
__device__ __forceinline__ int bucket2(int rel) {
  int ret = rel > 0 ? 32 : 0;
  int n = rel < 0 ? -rel : rel;
  if (n < 16) return ret + n;
  int v = 16 + (int)(log2v((float)n * 0.0625f) * 4.0f);
  return ret + (v < 31 ? v : 31);
}

// Bias precompute -> fp8 e4m3 table. Layout: [b][h][qt32][kt32][tid256][16]
// fp8 bytes, sub = fn*4+r with swapped-attn mapping (q-row = w*16+(l&15),
// kv = fn*16+(l>>4)*4+r). Values pre-scaled by log2(e); mask -> sat(-448).
__global__ __launch_bounds__(256) void k_bias(
    const int* __restrict__ pos, const int* __restrict__ bbx,
    const unsigned char* __restrict__ msk,
    const float* __restrict__ wp, const float* __restrict__ wx,
    const float* __restrict__ wy, u8* __restrict__ bias) {
  int bid = blockIdx.x;                 // b*1024 + qt*32 + kt
  int b = bid >> 10, qt = (bid >> 5) & 31, kt = bid & 31;
  __shared__ __align__(16) float swpT[3][32][4], swxT[3][64][4], swyT[3][64][4];
  __shared__ int pq[64], xq[64], yq[64], pk[64], xk[64], yk[64];
  __shared__ unsigned char mk[64];
  int t = threadIdx.x;
  for (int i = t; i < 384; i += 256) {
    int g = i >> 7, idx = i & 127;
    swpT[g][idx >> 2][idx & 3] = wp[(g * 4 + (idx & 3)) * 32 + (idx >> 2)] * LOG2E;
  }
  for (int i = t; i < 768; i += 256) {
    int g = i >> 8, idx = i & 255;
    swxT[g][idx >> 2][idx & 3] = wx[(g * 4 + (idx & 3)) * 64 + (idx >> 2)] * LOG2E;
    swyT[g][idx >> 2][idx & 3] = wy[(g * 4 + (idx & 3)) * 64 + (idx >> 2)] * LOG2E;
  }
  int q0 = qt * 64, k0 = kt * 64;
  if (t < 64) {
    int gi = b * SS + q0 + t;
    pq[t] = pos[gi]; xq[t] = bbx[gi * 4]; yq[t] = bbx[gi * 4 + 3];
  } else if (t < 128) {
    int j = t - 64, gi = b * SS + k0 + j;
    pk[j] = pos[gi]; xk[j] = bbx[gi * 4]; yk[j] = bbx[gi * 4 + 3];
    mk[j] = msk[b * SS + k0 + j];
  }
  __syncthreads();
  int w = t >> 6, l = t & 63;
  int hi = l >> 4;
  int qlr = w * 16 + (l & 15);
  int pql = pq[qlr], xql = xq[qlr], yql = yq[qlr];
  int packed[16];
#pragma unroll
  for (int fn = 0; fn < 4; fn++)
#pragma unroll
    for (int r = 0; r < 4; r++) {
      int kl = fn * 16 + hi * 4 + r;
      int b1 = bucket1(pk[kl] - pql);
      int b2 = bucket2(xk[kl] - xql);
      int b3 = bucket2(yk[kl] - yql);
      packed[fn * 4 + r] = b1 | (b2 << 5) | (b3 << 11) | (mk[kl] ? (1 << 17) : 0);
    }
  for (int hg = 0; hg < 3; hg++) {
    unsigned words[4][4];  // [head][word]
#pragma unroll
    for (int j2 = 0; j2 < 8; j2++) {
      float a0[4], a1[4];
      {
        int p = packed[2 * j2];
        f32x4 ap = *(const f32x4*)swpT[hg][p & 31];
        f32x4 bx = *(const f32x4*)swxT[hg][(p >> 5) & 63];
        f32x4 cy = *(const f32x4*)swyT[hg][(p >> 11) & 63];
        bool mm = (p >> 17) != 0;
#pragma unroll
        for (int hh = 0; hh < 4; hh++)
          a0[hh] = mm ? -3.0e38f : (ap[hh] + bx[hh] + cy[hh]);
      }
      {
        int p = packed[2 * j2 + 1];
        f32x4 ap = *(const f32x4*)swpT[hg][p & 31];
        f32x4 bx = *(const f32x4*)swxT[hg][(p >> 5) & 63];
        f32x4 cy = *(const f32x4*)swyT[hg][(p >> 11) & 63];
        bool mm = (p >> 17) != 0;
#pragma unroll
        for (int hh = 0; hh < 4; hh++)
          a1[hh] = mm ? -3.0e38f : (ap[hh] + bx[hh] + cy[hh]);
      }
      int wd = j2 >> 1;
      if ((j2 & 1) == 0) {
#pragma unroll
        for (int hh = 0; hh < 4; hh++)
          words[hh][wd] = __builtin_amdgcn_cvt_pk_fp8_f32(a0[hh], a1[hh], 0, false);
      } else {
#pragma unroll
        for (int hh = 0; hh < 4; hh++)
          words[hh][wd] = __builtin_amdgcn_cvt_pk_fp8_f32(a0[hh], a1[hh],
                                                          words[hh][wd], true);
      }
    }
#pragma unroll
    for (int hh = 0; hh < 4; hh++) {
      int h = hg * 4 + hh;
      u8* dst = bias +
          ((size_t)((b * 12 + h) * 1024 + qt * 32 + kt) * 256 + t) * 16;
      *(uint4*)dst = make_uint4(words[hh][0], words[hh][1], words[hh][2],
                                words[hh][3]);
    }
  }
}

// --------------------------------------------------------------------------
// ALL-layer weight convert fp32 -> bf16, transposed to [out][in], one launch
__global__ __launch_bounds__(256) void k_wconv_all(
    const float* __restrict__ qw, const float* __restrict__ kw,
    const float* __restrict__ vw, const float* __restrict__ ow,
    u16* __restrict__ wt) {
  int bid = blockIdx.x;                     // layer*576 + g*144 + nt*12 + kt
  int layer = bid / 576, rem = bid % 576;
  int g = rem / 144, rr_ = rem % 144, nt = rr_ / 12, kt = rr_ % 12;
  const float* src = g == 0 ? qw : g == 1 ? kw : g == 2 ? vw : ow;
  src += (size_t)layer * DD * DD;
  __shared__ float sm[64][67];
  int t = threadIdx.x, c2 = t & 31, r0 = t >> 5;
#pragma unroll
  for (int p = 0; p < 8; p++) {
    int row = r0 + p * 8;
    float2 v = *(const float2*)&src[(size_t)(kt * 64 + row) * DD + nt * 64 + c2 * 2];
    sm[row][c2 * 2] = v.x;
    sm[row][c2 * 2 + 1] = v.y;
  }
  __syncthreads();
  u16* dst = wt + (size_t)layer * WT_LSTRIDE + (size_t)g * DD * DD;
#pragma unroll
  for (int p = 0; p < 8; p++) {
    int n = r0 + p * 8;
    float v0 = sm[c2 * 2][n], v1 = sm[c2 * 2 + 1][n];
    *(unsigned*)&dst[(size_t)(nt * 64 + n) * DD + kt * 64 + c2 * 2] = cvtpk(v0, v1);
  }
}

// --------------------------------------------------------------------------
// GEMM core v2 (2-phase): C[128,128] = A[128,768] x Bt[128,768]^T, BK=64,
// double-buffered XOR-swizzled LDS; STAGE(t+1) issued BEFORE compute(t);
// ONE __syncthreads per K-step (drains stage + syncs readers).
__device__ __forceinline__ void gemm_core(const u16* __restrict__ A,
                                          const u16* __restrict__ Bt, u16* As,
                                          u16* Bs, f32x4 acc[4][4], int tid) {
  int w = tid >> 6, l = tid & 63;
  int wm = w >> 1, wn = w & 1;
#pragma unroll
  for (int i = 0; i < 4; i++)
#pragma unroll
    for (int j = 0; j < 4; j++) acc[i][j] = f32x4{0.f, 0.f, 0.f, 0.f};
  int r0 = w * 32;
  auto STG = [&](int kt, int buf) {
#pragma unroll
    for (int j = 0; j < 4; j++) {
      int row = r0 + j * 8 + (l >> 3);
      int sl = (l & 7) ^ (row & 7);
      g2lds16(A + (size_t)row * DD + kt * 64 + sl * 8,
              As + buf * 8192 + (r0 + j * 8) * 64);
      g2lds16(Bt + (size_t)row * DD + kt * 64 + sl * 8,
              Bs + buf * 8192 + (r0 + j * 8) * 64);
    }
  };
  STG(0, 0);
  __syncthreads();
  for (int kt = 0; kt < 12; kt++) {
    int buf = kt & 1;
    if (kt < 11) STG(kt + 1, buf ^ 1);
    const char* Ab = (const char*)(As + buf * 8192);
    const char* Bb = (const char*)(Bs + buf * 8192);
#pragma unroll
    for (int kk = 0; kk < 2; kk++) {
      bf16x8 af[4], bfr[4];
#pragma unroll
      for (int fm = 0; fm < 4; fm++) {
        int row = wm * 64 + fm * 16 + (l & 15);
        int slot = (kk * 4 + (l >> 4)) ^ (row & 7);
        af[fm] = *(const bf16x8*)(Ab + row * 128 + slot * 16);
      }
#pragma unroll
      for (int fn = 0; fn < 4; fn++) {
        int row = wn * 64 + fn * 16 + (l & 15);
        int slot = (kk * 4 + (l >> 4)) ^ (row & 7);
        bfr[fn] = *(const bf16x8*)(Bb + row * 128 + slot * 16);
      }
#pragma unroll
      for (int fm = 0; fm < 4; fm++)
#pragma unroll
        for (int fn = 0; fn < 4; fn++)
          acc[fm][fn] = __builtin_amdgcn_mfma_f32_16x16x32_bf16(
              af[fm], bfr[fn], acc[fm][fn], 0, 0, 0);
    }
    __syncthreads();
  }
}

// fused QKV GEMM (N = 3*768); q scaled by log2(e)/8; V written TRANSPOSED
__global__ __launch_bounds__(256) void k_gemm_qkv(
    const u16* __restrict__ hb, const u16* __restrict__ wt,
    const float* __restrict__ qbias, const float* __restrict__ kbias,
    const float* __restrict__ vbias, u16* __restrict__ qo, u16* __restrict__ ko,
    u16* __restrict__ vtb) {
  __shared__ __align__(16) u16 As[2 * 128 * 64];
  __shared__ __align__(16) u16 Bs[2 * 128 * 64];
  int bid0 = blockIdx.x;
  int bid = (bid0 & 7) * 72 + (bid0 >> 3);   // XCD chunk swizzle (576 = 8*72)
  int mblk = bid / 18, nblk = bid % 18;
  int g = nblk / 6, nb = nblk % 6;
  const u16* A = hb + (size_t)mblk * 128 * DD;
  const u16* Bt = wt + (size_t)g * DD * DD + (size_t)nb * 128 * DD;
  f32x4 acc[4][4];
  gemm_core(A, Bt, As, Bs, acc, threadIdx.x);
  int w = threadIdx.x >> 6, l = threadIdx.x & 63;
  int wm = w >> 1, wn = w & 1;
  int hi4 = (l >> 4) << 2;
  if (g == 2) {
    // V: write transposed [bh][d][s], packed 4-bf16 (s-contiguous) stores
#pragma unroll
    for (int fn = 0; fn < 4; fn++) {
      int col = nb * 128 + wn * 64 + fn * 16 + (l & 15);
      float bval = vbias[col];
      int h = col >> 6, d = col & 63;
#pragma unroll
      for (int fm = 0; fm < 4; fm++) {
        int row = mblk * 128 + wm * 64 + fm * 16 + hi4;
        int bb = row >> 11, s = row & 2047;
        unsigned p0 = cvtpk(acc[fm][fn][0] + bval, acc[fm][fn][1] + bval);
        unsigned p1 = cvtpk(acc[fm][fn][2] + bval, acc[fm][fn][3] + bval);
        *(uint2*)(vtb + ((size_t)(bb * 12 + h) * 64 + d) * 2048 + s) =
            make_uint2(p0, p1);
      }
    }
    return;
  }
  const float* bias = g == 0 ? qbias : kbias;
  u16* out = g == 0 ? qo : ko;
  float scale = g == 0 ? 0.125f * LOG2E : 1.0f;
#pragma unroll
  for (int fn = 0; fn < 4; fn++) {
    int col = nb * 128 + wn * 64 + fn * 16 + (l & 15);
    float bval = bias[col];
#pragma unroll
    for (int fm = 0; fm < 4; fm++)
#pragma unroll
      for (int r = 0; r < 4; r++) {
        int row = mblk * 128 + wm * 64 + fm * 16 + hi4 + r;
        out[(size_t)row * DD + col] = f2bf((acc[fm][fn][r] + bval) * scale);
      }
  }
}

// O-projection GEMM, bf16 output (residual+LN done in k_ln, fp32 residual)
__global__ __launch_bounds__(256) void k_gemm_o(const u16* __restrict__ ctx,
                                                const u16* __restrict__ wto,
                                                const float* __restrict__ obias,
                                                u16* __restrict__ outp) {
  __shared__ __align__(16) u16 As[2 * 128 * 64];
  __shared__ __align__(16) u16 Bs[2 * 128 * 64];
  int bid0 = blockIdx.x;
  int bid = (bid0 & 7) * 24 + (bid0 >> 3);   // XCD chunk swizzle (192 = 8*24)
  int mblk = bid / 6, nblk = bid % 6;
  const u16* A = ctx + (size_t)mblk * 128 * DD;
  const u16* Bt = wto + (size_t)nblk * 128 * DD;
  f32x4 acc[4][4];
  gemm_core(A, Bt, As, Bs, acc, threadIdx.x);
  int w = threadIdx.x >> 6, l = threadIdx.x & 63;
  int wm = w >> 1, wn = w & 1;
#pragma unroll
  for (int fn = 0; fn < 4; fn++) {
    int col = nblk * 128 + wn * 64 + fn * 16 + (l & 15);
    float bval = obias[col];
#pragma unroll
    for (int fm = 0; fm < 4; fm++)
#pragma unroll
      for (int r = 0; r < 4; r++) {
        int row = mblk * 128 + wm * 64 + fm * 16 + ((l >> 4) << 2) + r;
        outp[(size_t)row * DD + col] = f2bf(acc[fm][fn][r] + bval);
      }
  }
}

// --------------------------------------------------------------------------
// Flash attention v10: K double-buffered LDS; V fragments in REGISTERS,
// issued at tile top (latency hidden under QK+softmax, counted-vmcnt wait at
// PV leaves K-prefetch in flight); fp8 bias acc-init; ones-MFMA row-sum;
// defer-max THR=8; setprio; XCD swizzle. LDS = 24KB.
__global__ __launch_bounds__(256) void k_attn(
    const u16* __restrict__ qm, const u16* __restrict__ kmat,
    const u16* __restrict__ vt, const u8* __restrict__ bias,
    u16* __restrict__ ctx) {
  int bid0 = blockIdx.x;
  int bid = (bid0 & 7) * 96 + (bid0 >> 3);   // XCD chunk swizzle (768 = 8*96)
  int qt = bid & 31, bh = bid >> 5;
  int b = bh / 12, h = bh % 12;
  __shared__ __align__(16) u16 Ks[2][64 * 64];
  __shared__ __align__(16) u16 Ps[4][16 * 64];
  int tid = threadIdx.x, w = tid >> 6, l = tid & 63;
  int hi = l >> 4, qr = l & 15;
  int q0 = qt * 64;
  const u16* qp = qm + (size_t)(b * SS + q0 + w * 16 + qr) * DD + h * 64 +
                  hi * 8;
  bf16x8 aq0 = *(const bf16x8*)qp;
  bf16x8 aq1 = *(const bf16x8*)(qp + 32);
  const u16* kb_ = kmat + (size_t)(b * SS) * DD + h * 64;
  const u16* vb_ = vt + (size_t)bh * 64 * SS;
  const u16* vL = vb_ + (size_t)qr * SS + hi * 8;   // + fn*16*SS + kt*64 + ck*32
  const u8* bb_ = bias + ((size_t)(bh * 32 + qt) * 32 * 256 + tid) * 16;
  f32x4 oa[4];
#pragma unroll
  for (int fn = 0; fn < 4; fn++) oa[fn] = f32x4{0.f, 0.f, 0.f, 0.f};
  f32x4 lacc = f32x4{0.f, 0.f, 0.f, 0.f};
  float m_ = -3.0e38f;
  bf16x8 vones;
#pragma unroll
  for (int i = 0; i < 8; i++) vones[i] = (short)0x3F80;
  int srow = tid >> 3, sc8 = tid & 7;

  auto STAGE = [&](int kt, int buf) {
#pragma unroll
    for (int j = 0; j < 2; j++) {
      int rr = srow + j * 32;
      int sl = sc8 ^ (rr & 7);
      g2lds16(kb_ + (size_t)(kt * 64 + rr) * DD + sl * 8,
              &Ks[buf][tid * 8 + j * 2048]);
    }
  };

  STAGE(0, 0);
  uint4 bu = *(const uint4*)bb_;
  uint4 nb = bu;
  char* pw = (char*)&Ps[w][0] + qr * 128;
  int qs = (qr & 7) << 4;
  __syncthreads();

  for (int kt = 0; kt < 32; kt++) {
    int buf = kt & 1;
    // issue V(kt) fragment loads FIRST (consumed at PV below; QK+softmax
    // covers the latency; PV's wait is counted, leaves K-stage in flight)
    bf16x8 cv[8];
#pragma unroll
    for (int ck = 0; ck < 2; ck++)
#pragma unroll
      for (int fn = 0; fn < 4; fn++)
        cv[ck * 4 + fn] = *(const bf16x8*)(vL + (size_t)fn * 16 * SS +
                                           kt * 64 + ck * 32);
    if (kt < 31) {
      STAGE(kt + 1, buf ^ 1);
      nb = *(const uint4*)(bb_ + (size_t)(kt + 1) * 4096);
    }
    // acc-init from fp8 bias (word fn holds subs fn*4..fn*4+3)
    f32x4 sc[4];
    {
      unsigned uw[4] = {bu.x, bu.y, bu.z, bu.w};
#pragma unroll
      for (int fn = 0; fn < 4; fn++) {
        f32x2 p0 = __builtin_amdgcn_cvt_pk_f32_fp8(uw[fn], false);
        f32x2 p1 = __builtin_amdgcn_cvt_pk_f32_fp8(uw[fn], true);
        sc[fn][0] = p0.x; sc[fn][1] = p0.y; sc[fn][2] = p1.x; sc[fn][3] = p1.y;
      }
    }
    __builtin_amdgcn_s_setprio(1);
#pragma unroll
    for (int kk = 0; kk < 2; kk++) {
      bf16x8 aq = kk == 0 ? aq0 : aq1;
#pragma unroll
      for (int fn = 0; fn < 4; fn++) {
        int row = fn * 16 + qr;
        int slot = (kk * 4 + hi) ^ (row & 7);
        bf16x8 bk = *(const bf16x8*)((const char*)&Ks[buf][0] + row * 128 +
                                     slot * 16);
        sc[fn] = __builtin_amdgcn_mfma_f32_16x16x32_bf16(bk, aq, sc[fn],
                                                         0, 0, 0);
      }
    }
    __builtin_amdgcn_s_setprio(0);
    // per-lane online softmax (base-2), defer-max threshold 8
    float pa = max3f(sc[0][0], sc[0][1], sc[0][2]);
    float pb = max3f(sc[0][3], sc[1][0], sc[1][1]);
    pa = max3f(pa, sc[1][2], sc[1][3]);
    pb = max3f(pb, sc[2][0], sc[2][1]);
    pa = max3f(pa, sc[2][2], sc[2][3]);
    pb = max3f(pb, sc[3][0], sc[3][1]);
    pa = max3f(pa, sc[3][2], sc[3][3]);
    float pm = fmaxf(pa, pb);
    pm = fmaxf(pm, __shfl_xor(pm, 16));
    pm = fmaxf(pm, __shfl_xor(pm, 32));
    if (__any(pm > m_ + 8.f)) {
      float mn = fmaxf(m_, pm);
      float f = exp2v(m_ - mn);
#pragma unroll
      for (int fn = 0; fn < 4; fn++)
#pragma unroll
        for (int r = 0; r < 4; r++) oa[fn][r] *= f;
#pragma unroll
      for (int r = 0; r < 4; r++) lacc[r] *= f;
      m_ = mn;
    }
#pragma unroll
    for (int fn = 0; fn < 4; fn++)
#pragma unroll
      for (int r = 0; r < 4; r++) sc[fn][r] = exp2v(sc[fn][r] - m_);
    // pack P (kv-contig per lane) -> per-wave swizzled LDS, 4x b64 writes
#pragma unroll
    for (int fn = 0; fn < 4; fn++) {
      unsigned w0 = cvtpk(sc[fn][0], sc[fn][1]);
      unsigned w1 = cvtpk(sc[fn][2], sc[fn][3]);
      *(uint2*)(pw + ((fn * 32 + hi * 8) ^ qs)) = make_uint2(w0, w1);
    }
    // PV: O^T += V^T(regs) x P^T; row-sum via ones-MFMA
    __builtin_amdgcn_s_setprio(1);
#pragma unroll
    for (int ck = 0; ck < 2; ck++) {
      bf16x8 pt = *(const bf16x8*)(pw + ((ck * 64 + hi * 16) ^ qs));
#pragma unroll
      for (int fn = 0; fn < 4; fn++)
        oa[fn] = __builtin_amdgcn_mfma_f32_16x16x32_bf16(cv[ck * 4 + fn], pt,
                                                         oa[fn], 0, 0, 0);
      lacc = __builtin_amdgcn_mfma_f32_16x16x32_bf16(vones, pt, lacc, 0, 0, 0);
    }
    __builtin_amdgcn_s_setprio(0);
    bu = nb;
    __syncthreads();
  }
  // epilogue: normalize + packed 8B stores (d = fn*16 + hi*4 + 0..3)
  float inv = 1.0f / lacc[0];
  u16* cp = ctx + (size_t)(b * SS + q0 + w * 16 + qr) * DD + h * 64 + hi * 4;
#pragma unroll
  for (int fn = 0; fn < 4; fn++) {
    unsigned w0 = cvtpk(oa[fn][0] * inv, oa[fn][1] * inv);
    unsigned w1 = cvtpk(oa[fn][2] * inv, oa[fn][3] * inv);
    *(uint2*)(cp + fn * 16) = make_uint2(w0, w1);
  }
}

// --------------------------------------------------------------------------
// residual + LayerNorm: x bf16 (o-proj out), res fp32; one wave per row.
__global__ __launch_bounds__(256) void k_ln(const u16* __restrict__ x,
                                            const float* __restrict__ res,
                                            const float* __restrict__ g,
                                            const float* __restrict__ bta,
                                            float* __restrict__ ho,
                                            u16* __restrict__ hbo) {
  int w = threadIdx.x >> 6, l = threadIdx.x & 63;
  int row = blockIdx.x * 4 + w;
  const u16* xr = x + (size_t)row * DD;
  const float* rr = res + (size_t)row * DD;
  float v[12];
  float s = 0.f, s2 = 0.f;
#pragma unroll
  for (int j = 0; j < 3; j++) {
    int c = j * 256 + l * 4;
    uint2 xv = *(const uint2*)(xr + c);
    float4 rv = *(const float4*)(rr + c);
    float a0 = bf2f(xv.x & 0xffffu) + rv.x;
    float a1 = bf2f(xv.x >> 16) + rv.y;
    float a2 = bf2f(xv.y & 0xffffu) + rv.z;
    float a3 = bf2f(xv.y >> 16) + rv.w;
    v[j * 4 + 0] = a0; v[j * 4 + 1] = a1; v[j * 4 + 2] = a2; v[j * 4 + 3] = a3;
    s += (a0 + a1) + (a2 + a3);
    s2 += (a0 * a0 + a1 * a1) + (a2 * a2 + a3 * a3);
  }
#pragma unroll
  for (int m = 1; m < 64; m <<= 1) {
    s += __shfl_xor(s, m);
    s2 += __shfl_xor(s2, m);
  }
  float mean = s * (1.f / 768.f);
  float var = s2 * (1.f / 768.f) - mean * mean;
  float rstd = rsqrtf(var + 1e-12f);
#pragma unroll
  for (int j = 0; j < 3; j++) {
    int c = j * 256 + l * 4;
    float4 gv = *(const float4*)(g + c);
    float4 bv = *(const float4*)(bta + c);
    float y0 = (v[j * 4 + 0] - mean) * rstd * gv.x + bv.x;
    float y1 = (v[j * 4 + 1] - mean) * rstd * gv.y + bv.y;
    float y2 = (v[j * 4 + 2] - mean) * rstd * gv.z + bv.z;
    float y3 = (v[j * 4 + 3] - mean) * rstd * gv.w + bv.w;
    *(float4*)(ho + (size_t)row * DD + c) = make_float4(y0, y1, y2, y3);
    *(uint2*)(hbo + (size_t)row * DD + c) =
        make_uint2(cvtpk(y0, y1), cvtpk(y2, y3));
  }
}

// --------------------------------------------------------------------------
extern "C" void kernel_launch(void* const* d_in, const int* in_sizes, int n_in,
                              void* d_out, int out_size, void* d_ws,
                              size_t ws_size, hipStream_t stream) {
  const float* hid = (const float*)d_in[0];
  const unsigned char* msk = (const unsigned char*)d_in[1];
  const int* pos = (const int*)d_in[2];
  const int* bbx = (const int*)d_in[3];
  const float* qw = (const float*)d_in[4];
  const float* qbv = (const float*)d_in[5];
  const float* kw = (const float*)d_in[6];
  const float* kbv = (const float*)d_in[7];
  const float* vw = (const float*)d_in[8];
  const float* vbv = (const float*)d_in[9];
  const float* ow = (const float*)d_in[10];
  const float* obv = (const float*)d_in[11];
  const float* lng = (const float*)d_in[12];
  const float* lnb = (const float*)d_in[13];
  const float* wpb = (const float*)d_in[14];
  const float* wxb = (const float*)d_in[15];
  const float* wyb = (const float*)d_in[16];
  float* outp = (float*)d_out;

  // workspace carve (~201 MiB)
  char* p = (char*)d_ws;
  u8* bias = (u8*)p;     p += (size_t)100663296;  // [B,H,S,S] fp8, pre-blocked
  float* hbuf = (float*)p; p += 12582912;         // residual stream fp32
  u16* hb = (u16*)p;     p += 6291456;            // h in bf16
  u16* qo = (u16*)p;     p += 6291456;
  u16* ko = (u16*)p;     p += 6291456;
  u16* vtb = (u16*)p;    p += 6291456;            // V transposed [BH][64][S]
  u16* ctxb = (u16*)p;   p += 6291456;
  u16* wtb = (u16*)p;    p += (size_t)56623104;   // ALL layers wT bf16
  u16* att = qo;                                  // alias q (dead by O-GEMM)

  k_hb<<<dim3(3072), dim3(256), 0, stream>>>((const float4*)hid, (uint2*)hb,
                                             786432);
  k_bias<<<dim3(2048), dim3(256), 0, stream>>>(pos, bbx, msk, wpb, wxb, wyb,
                                               bias);
  k_wconv_all<<<dim3(6912), dim3(256), 0, stream>>>(qw, kw, vw, ow, wtb);
  for (int l = 0; l < NLAYER; l++) {
    const u16* wl = wtb + (size_t)l * WT_LSTRIDE;
    k_gemm_qkv<<<dim3(576), dim3(256), 0, stream>>>(
        hb, wl, qbv + l * DD, kbv + l * DD, vbv + l * DD, qo, ko, vtb);
    k_attn<<<dim3(768), dim3(256), 0, stream>>>(qo, ko, vtb, bias, ctxb);
    k_gemm_o<<<dim3(192), dim3(256), 0, stream>>>(
        ctxb, wl + (size_t)3 * DD * DD, obv + l * DD, att);
    k_ln<<<dim3(1024), dim3(256), 0, stream>>>(
        att, l == 0 ? hid : (const float*)hbuf, lng + l * DD, lnb + l * DD,
        l == 11 ? outp : hbuf, hb);
  }
}

// Round 13
// 1383.908 us; speedup vs baseline: 1.4089x; 1.4089x over previous
//
#include <hip/hip_runtime.h>

// ---------------------------------------------------------------------------
// ErnieLayout encoder, 12 layers, B=2 S=2048 D=768 H=12 DH=64, bf16 MFMA.
// r13: attn reverted to r11 (K+V via g2lds LDS — V-from-global is
// twice-measured bad); keep 2-phase GEMM core, bf16 o-proj, hw-log2 bias,
// batched wconv, XCD swizzles, fp8 bias acc-init, ones-MFMA, defer-max.
// ---------------------------------------------------------------------------

#define BB 2
#define SS 2048
#define DD 768
#define HH 12
#define NLAYER 12
#define MM 4096  // BB*SS

typedef unsigned short u16;
typedef unsigned char u8;
typedef __attribute__((ext_vector_type(8))) short bf16x8;
typedef __attribute__((ext_vector_type(4))) float f32x4;
typedef __attribute__((ext_vector_type(2))) float f32x2;

#define LOG2E 1.44269504088896340736f
#define WT_LSTRIDE 2359296  // per-layer u16 elements in wtb (4*768*768)

__device__ __forceinline__ u16 f2bf(float f) {
  unsigned u = __float_as_uint(f);
  unsigned r = (u + 0x7FFFu + ((u >> 16) & 1u)) >> 16;
  return (u16)r;
}
__device__ __forceinline__ float bf2f(unsigned u) {
  return __uint_as_float(u << 16);
}
__device__ __forceinline__ unsigned cvtpk(float a, float b) {
  unsigned r;
  asm("v_cvt_pk_bf16_f32 %0, %1, %2" : "=v"(r) : "v"(a), "v"(b));
  return r;
}
__device__ __forceinline__ float exp2v(float x) {
  float r;
  asm("v_exp_f32 %0, %1" : "=v"(r) : "v"(x));
  return r;
}
__device__ __forceinline__ float log2v(float x) {
  float r;
  asm("v_log_f32 %0, %1" : "=v"(r) : "v"(x));
  return r;
}
__device__ __forceinline__ float max3f(float a, float b, float c) {
  float r;
  asm("v_max3_f32 %0, %1, %2, %3" : "=v"(r) : "v"(a), "v"(b), "v"(c));
  return r;
}

__device__ __forceinline__ void g2lds16(const void* g, void* l) {
  __builtin_amdgcn_global_load_lds(
      (const __attribute__((address_space(1))) unsigned int*)g,
      (__attribute__((address_space(3))) unsigned int*)l, 16, 0, 0);
}

// --------------------------------------------------------------------------
// hidden fp32 -> bf16
__global__ __launch_bounds__(256) void k_hb(const float4* __restrict__ x,
                                            uint2* __restrict__ o, int n4) {
  int i = blockIdx.x * 256 + threadIdx.x;
  if (i < n4) {
    float4 v = x[i];
    uint2 r;
    r.x = (unsigned)f2bf(v.x) | ((unsigned)f2bf(v.y) << 16);
    r.y = (unsigned)f2bf(v.z) | ((unsigned)f2bf(v.w) << 16);
    o[i] = r;
  }
}

// --------------------------------------------------------------------------
// relative-position bucketing; hardware log2 (exact algebraic rewrite)
__device__ __forceinline__ int bucket1(int rel) {
  int ret = rel > 0 ? 16 : 0;
  int n = rel < 0 ? -rel : rel;
  if (n < 8) return ret + n;
  int v = 8 + (int)(log2v((float)n * 0.125f) * 2.0f);
  return ret + (v < 15 ? v : 15);
}
__device__ __forceinline__ int bucket2(int rel) {
  int ret = rel > 0 ? 32 : 0;
  int n = rel < 0 ? -rel : rel;
  if (n < 16) return ret + n;
  int v = 16 + (int)(log2v((float)n * 0.0625f) * 4.0f);
  return ret + (v < 31 ? v : 31);
}

// Bias precompute -> fp8 e4m3 table. Layout: [b][h][qt32][kt32][tid256][16]
// fp8 bytes, sub = fn*4+r with swapped-attn mapping (q-row = w*16+(l&15),
// kv = fn*16+(l>>4)*4+r). Values pre-scaled by log2(e); mask -> sat(-448).
__global__ __launch_bounds__(256) void k_bias(
    const int* __restrict__ pos, const int* __restrict__ bbx,
    const unsigned char* __restrict__ msk,
    const float* __restrict__ wp, const float* __restrict__ wx,
    const float* __restrict__ wy, u8* __restrict__ bias) {
  int bid = blockIdx.x;                 // b*1024 + qt*32 + kt
  int b = bid >> 10, qt = (bid >> 5) & 31, kt = bid & 31;
  __shared__ __align__(16) float swpT[3][32][4], swxT[3][64][4], swyT[3][64][4];
  __shared__ int pq[64], xq[64], yq[64], pk[64], xk[64], yk[64];
  __shared__ unsigned char mk[64];
  int t = threadIdx.x;
  for (int i = t; i < 384; i += 256) {
    int g = i >> 7, idx = i & 127;
    swpT[g][idx >> 2][idx & 3] = wp[(g * 4 + (idx & 3)) * 32 + (idx >> 2)] * LOG2E;
  }
  for (int i = t; i < 768; i += 256) {
    int g = i >> 8, idx = i & 255;
    swxT[g][idx >> 2][idx & 3] = wx[(g * 4 + (idx & 3)) * 64 + (idx >> 2)] * LOG2E;
    swyT[g][idx >> 2][idx & 3] = wy[(g * 4 + (idx & 3)) * 64 + (idx >> 2)] * LOG2E;
  }
  int q0 = qt * 64, k0 = kt * 64;
  if (t < 64) {
    int gi = b * SS + q0 + t;
    pq[t] = pos[gi]; xq[t] = bbx[gi * 4]; yq[t] = bbx[gi * 4 + 3];
  } else if (t < 128) {
    int j = t - 64, gi = b * SS + k0 + j;
    pk[j] = pos[gi]; xk[j] = bbx[gi * 4]; yk[j] = bbx[gi * 4 + 3];
    mk[j] = msk[b * SS + k0 + j];
  }
  __syncthreads();
  int w = t >> 6, l = t & 63;
  int hi = l >> 4;
  int qlr = w * 16 + (l & 15);
  int pql = pq[qlr], xql = xq[qlr], yql = yq[qlr];
  int packed[16];
#pragma unroll
  for (int fn = 0; fn < 4; fn++)
#pragma unroll
    for (int r = 0; r < 4; r++) {
      int kl = fn * 16 + hi * 4 + r;
      int b1 = bucket1(pk[kl] - pql);
      int b2 = bucket2(xk[kl] - xql);
      int b3 = bucket2(yk[kl] - yql);
      packed[fn * 4 + r] = b1 | (b2 << 5) | (b3 << 11) | (mk[kl] ? (1 << 17) : 0);
    }
  for (int hg = 0; hg < 3; hg++) {
    unsigned words[4][4];  // [head][word]
#pragma unroll
    for (int j2 = 0; j2 < 8; j2++) {
      float a0[4], a1[4];
      {
        int p = packed[2 * j2];
        f32x4 ap = *(const f32x4*)swpT[hg][p & 31];
        f32x4 bx = *(const f32x4*)swxT[hg][(p >> 5) & 63];
        f32x4 cy = *(const f32x4*)swyT[hg][(p >> 11) & 63];
        bool mm = (p >> 17) != 0;
#pragma unroll
        for (int hh = 0; hh < 4; hh++)
          a0[hh] = mm ? -3.0e38f : (ap[hh] + bx[hh] + cy[hh]);
      }
      {
        int p = packed[2 * j2 + 1];
        f32x4 ap = *(const f32x4*)swpT[hg][p & 31];
        f32x4 bx = *(const f32x4*)swxT[hg][(p >> 5) & 63];
        f32x4 cy = *(const f32x4*)swyT[hg][(p >> 11) & 63];
        bool mm = (p >> 17) != 0;
#pragma unroll
        for (int hh = 0; hh < 4; hh++)
          a1[hh] = mm ? -3.0e38f : (ap[hh] + bx[hh] + cy[hh]);
      }
      int wd = j2 >> 1;
      if ((j2 & 1) == 0) {
#pragma unroll
        for (int hh = 0; hh < 4; hh++)
          words[hh][wd] = __builtin_amdgcn_cvt_pk_fp8_f32(a0[hh], a1[hh], 0, false);
      } else {
#pragma unroll
        for (int hh = 0; hh < 4; hh++)
          words[hh][wd] = __builtin_amdgcn_cvt_pk_fp8_f32(a0[hh], a1[hh],
                                                          words[hh][wd], true);
      }
    }
#pragma unroll
    for (int hh = 0; hh < 4; hh++) {
      int h = hg * 4 + hh;
      u8* dst = bias +
          ((size_t)((b * 12 + h) * 1024 + qt * 32 + kt) * 256 + t) * 16;
      *(uint4*)dst = make_uint4(words[hh][0], words[hh][1], words[hh][2],
                                words[hh][3]);
    }
  }
}

// --------------------------------------------------------------------------
// ALL-layer weight convert fp32 -> bf16, transposed to [out][in], one launch
__global__ __launch_bounds__(256) void k_wconv_all(
    const float* __restrict__ qw, const float* __restrict__ kw,
    const float* __restrict__ vw, const float* __restrict__ ow,
    u16* __restrict__ wt) {
  int bid = blockIdx.x;                     // layer*576 + g*144 + nt*12 + kt
  int layer = bid / 576, rem = bid % 576;
  int g = rem / 144, rr_ = rem % 144, nt = rr_ / 12, kt = rr_ % 12;
  const float* src = g == 0 ? qw : g == 1 ? kw : g == 2 ? vw : ow;
  src += (size_t)layer * DD * DD;
  __shared__ float sm[64][67];
  int t = threadIdx.x, c2 = t & 31, r0 = t >> 5;
#pragma unroll
  for (int p = 0; p < 8; p++) {
    int row = r0 + p * 8;
    float2 v = *(const float2*)&src[(size_t)(kt * 64 + row) * DD + nt * 64 + c2 * 2];
    sm[row][c2 * 2] = v.x;
    sm[row][c2 * 2 + 1] = v.y;
  }
  __syncthreads();
  u16* dst = wt + (size_t)layer * WT_LSTRIDE + (size_t)g * DD * DD;
#pragma unroll
  for (int p = 0; p < 8; p++) {
    int n = r0 + p * 8;
    float v0 = sm[c2 * 2][n], v1 = sm[c2 * 2 + 1][n];
    *(unsigned*)&dst[(size_t)(nt * 64 + n) * DD + kt * 64 + c2 * 2] = cvtpk(v0, v1);
  }
}

// --------------------------------------------------------------------------
// GEMM core (2-phase): C[128,128] = A[128,768] x Bt[128,768]^T, BK=64,
// double-buffered XOR-swizzled LDS; STAGE(t+1) issued BEFORE compute(t);
// ONE __syncthreads per K-step.
__device__ __forceinline__ void gemm_core(const u16* __restrict__ A,
                                          const u16* __restrict__ Bt, u16* As,
                                          u16* Bs, f32x4 acc[4][4], int tid) {
  int w = tid >> 6, l = tid & 63;
  int wm = w >> 1, wn = w & 1;
#pragma unroll
  for (int i = 0; i < 4; i++)
#pragma unroll
    for (int j = 0; j < 4; j++) acc[i][j] = f32x4{0.f, 0.f, 0.f, 0.f};
  int r0 = w * 32;
  auto STG = [&](int kt, int buf) {
#pragma unroll
    for (int j = 0; j < 4; j++) {
      int row = r0 + j * 8 + (l >> 3);
      int sl = (l & 7) ^ (row & 7);
      g2lds16(A + (size_t)row * DD + kt * 64 + sl * 8,
              As + buf * 8192 + (r0 + j * 8) * 64);
      g2lds16(Bt + (size_t)row * DD + kt * 64 + sl * 8,
              Bs + buf * 8192 + (r0 + j * 8) * 64);
    }
  };
  STG(0, 0);
  __syncthreads();
  for (int kt = 0; kt < 12; kt++) {
    int buf = kt & 1;
    if (kt < 11) STG(kt + 1, buf ^ 1);
    const char* Ab = (const char*)(As + buf * 8192);
    const char* Bb = (const char*)(Bs + buf * 8192);
#pragma unroll
    for (int kk = 0; kk < 2; kk++) {
      bf16x8 af[4], bfr[4];
#pragma unroll
      for (int fm = 0; fm < 4; fm++) {
        int row = wm * 64 + fm * 16 + (l & 15);
        int slot = (kk * 4 + (l >> 4)) ^ (row & 7);
        af[fm] = *(const bf16x8*)(Ab + row * 128 + slot * 16);
      }
#pragma unroll
      for (int fn = 0; fn < 4; fn++) {
        int row = wn * 64 + fn * 16 + (l & 15);
        int slot = (kk * 4 + (l >> 4)) ^ (row & 7);
        bfr[fn] = *(const bf16x8*)(Bb + row * 128 + slot * 16);
      }
#pragma unroll
      for (int fm = 0; fm < 4; fm++)
#pragma unroll
        for (int fn = 0; fn < 4; fn++)
          acc[fm][fn] = __builtin_amdgcn_mfma_f32_16x16x32_bf16(
              af[fm], bfr[fn], acc[fm][fn], 0, 0, 0);
    }
    __syncthreads();
  }
}

// fused QKV GEMM (N = 3*768); q scaled by log2(e)/8; V written TRANSPOSED
__global__ __launch_bounds__(256) void k_gemm_qkv(
    const u16* __restrict__ hb, const u16* __restrict__ wt,
    const float* __restrict__ qbias, const float* __restrict__ kbias,
    const float* __restrict__ vbias, u16* __restrict__ qo, u16* __restrict__ ko,
    u16* __restrict__ vtb) {
  __shared__ __align__(16) u16 As[2 * 128 * 64];
  __shared__ __align__(16) u16 Bs[2 * 128 * 64];
  int bid0 = blockIdx.x;
  int bid = (bid0 & 7) * 72 + (bid0 >> 3);   // XCD chunk swizzle (576 = 8*72)
  int mblk = bid / 18, nblk = bid % 18;
  int g = nblk / 6, nb = nblk % 6;
  const u16* A = hb + (size_t)mblk * 128 * DD;
  const u16* Bt = wt + (size_t)g * DD * DD + (size_t)nb * 128 * DD;
  f32x4 acc[4][4];
  gemm_core(A, Bt, As, Bs, acc, threadIdx.x);
  int w = threadIdx.x >> 6, l = threadIdx.x & 63;
  int wm = w >> 1, wn = w & 1;
  int hi4 = (l >> 4) << 2;
  if (g == 2) {
    // V: write transposed [bh][d][s], packed 4-bf16 (s-contiguous) stores
#pragma unroll
    for (int fn = 0; fn < 4; fn++) {
      int col = nb * 128 + wn * 64 + fn * 16 + (l & 15);
      float bval = vbias[col];
      int h = col >> 6, d = col & 63;
#pragma unroll
      for (int fm = 0; fm < 4; fm++) {
        int row = mblk * 128 + wm * 64 + fm * 16 + hi4;
        int bb = row >> 11, s = row & 2047;
        unsigned p0 = cvtpk(acc[fm][fn][0] + bval, acc[fm][fn][1] + bval);
        unsigned p1 = cvtpk(acc[fm][fn][2] + bval, acc[fm][fn][3] + bval);
        *(uint2*)(vtb + ((size_t)(bb * 12 + h) * 64 + d) * 2048 + s) =
            make_uint2(p0, p1);
      }
    }
    return;
  }
  const float* bias = g == 0 ? qbias : kbias;
  u16* out = g == 0 ? qo : ko;
  float scale = g == 0 ? 0.125f * LOG2E : 1.0f;
#pragma unroll
  for (int fn = 0; fn < 4; fn++) {
    int col = nb * 128 + wn * 64 + fn * 16 + (l & 15);
    float bval = bias[col];
#pragma unroll
    for (int fm = 0; fm < 4; fm++)
#pragma unroll
      for (int r = 0; r < 4; r++) {
        int row = mblk * 128 + wm * 64 + fm * 16 + hi4 + r;
        out[(size_t)row * DD + col] = f2bf((acc[fm][fn][r] + bval) * scale);
      }
  }
}

// O-projection GEMM, bf16 output (residual+LN done in k_ln, fp32 residual)
__global__ __launch_bounds__(256) void k_gemm_o(const u16* __restrict__ ctx,
                                                const u16* __restrict__ wto,
                                                const float* __restrict__ obias,
                                                u16* __restrict__ outp) {
  __shared__ __align__(16) u16 As[2 * 128 * 64];
  __shared__ __align__(16) u16 Bs[2 * 128 * 64];
  int bid0 = blockIdx.x;
  int bid = (bid0 & 7) * 24 + (bid0 >> 3);   // XCD chunk swizzle (192 = 8*24)
  int mblk = bid / 6, nblk = bid % 6;
  const u16* A = ctx + (size_t)mblk * 128 * DD;
  const u16* Bt = wto + (size_t)nblk * 128 * DD;
  f32x4 acc[4][4];
  gemm_core(A, Bt, As, Bs, acc, threadIdx.x);
  int w = threadIdx.x >> 6, l = threadIdx.x & 63;
  int wm = w >> 1, wn = w & 1;
#pragma unroll
  for (int fn = 0; fn < 4; fn++) {
    int col = nblk * 128 + wn * 64 + fn * 16 + (l & 15);
    float bval = obias[col];
#pragma unroll
    for (int fm = 0; fm < 4; fm++)
#pragma unroll
      for (int r = 0; r < 4; r++) {
        int row = mblk * 128 + wm * 64 + fm * 16 + ((l >> 4) << 2) + r;
        outp[(size_t)row * DD + col] = f2bf(acc[fm][fn][r] + bval);
      }
  }
}

// --------------------------------------------------------------------------
// Flash attention (r11): swapped operands; K,V double-buffered g2lds LDS;
// fp8 bias acc-init; ones-MFMA row-sum; defer-max THR=8; setprio; XCD swz.
__global__ __launch_bounds__(256) void k_attn(
    const u16* __restrict__ qm, const u16* __restrict__ kmat,
    const u16* __restrict__ vt, const u8* __restrict__ bias,
    u16* __restrict__ ctx) {
  int bid0 = blockIdx.x;
  int bid = (bid0 & 7) * 96 + (bid0 >> 3);   // XCD chunk swizzle (768 = 8*96)
  int qt = bid & 31, bh = bid >> 5;
  int b = bh / 12, h = bh % 12;
  __shared__ __align__(16) u16 Ks[2][64 * 64];
  __shared__ __align__(16) u16 Vs[2][64 * 64];
  __shared__ __align__(16) u16 Ps[4][16 * 64];
  int tid = threadIdx.x, w = tid >> 6, l = tid & 63;
  int hi = l >> 4, qr = l & 15;
  int q0 = qt * 64;
  const u16* qp = qm + (size_t)(b * SS + q0 + w * 16 + qr) * DD + h * 64 +
                  hi * 8;
  bf16x8 aq0 = *(const bf16x8*)qp;
  bf16x8 aq1 = *(const bf16x8*)(qp + 32);
  const u16* kb_ = kmat + (size_t)(b * SS) * DD + h * 64;
  const u16* vb_ = vt + (size_t)bh * 64 * SS;
  const u8* bb_ = bias + ((size_t)(bh * 32 + qt) * 32 * 256 + tid) * 16;
  f32x4 oa[4];
#pragma unroll
  for (int fn = 0; fn < 4; fn++) oa[fn] = f32x4{0.f, 0.f, 0.f, 0.f};
  f32x4 lacc = f32x4{0.f, 0.f, 0.f, 0.f};
  float m_ = -3.0e38f;
  bf16x8 vones;
#pragma unroll
  for (int i = 0; i < 8; i++) vones[i] = (short)0x3F80;
  int srow = tid >> 3, sc8 = tid & 7;

  auto STAGE = [&](int kt, int buf) {
#pragma unroll
    for (int j = 0; j < 2; j++) {
      int rr = srow + j * 32;
      int sl = sc8 ^ (rr & 7);
      g2lds16(kb_ + (size_t)(kt * 64 + rr) * DD + sl * 8,
              &Ks[buf][tid * 8 + j * 2048]);
      g2lds16(vb_ + (size_t)rr * SS + kt * 64 + sl * 8,
              &Vs[buf][tid * 8 + j * 2048]);
    }
  };

  STAGE(0, 0);
  uint4 bu = *(const uint4*)bb_;
  uint4 nb = bu;
  char* pw = (char*)&Ps[w][0] + qr * 128;
  int qs = (qr & 7) << 4;
  __syncthreads();

  for (int kt = 0; kt < 32; kt++) {
    int buf = kt & 1;
    if (kt < 31) {
      STAGE(kt + 1, buf ^ 1);
      nb = *(const uint4*)(bb_ + (size_t)(kt + 1) * 4096);
    }
    // acc-init from fp8 bias (word fn holds subs fn*4..fn*4+3)
    f32x4 sc[4];
    {
      unsigned uw[4] = {bu.x, bu.y, bu.z, bu.w};
#pragma unroll
      for (int fn = 0; fn < 4; fn++) {
        f32x2 p0 = __builtin_amdgcn_cvt_pk_f32_fp8(uw[fn], false);
        f32x2 p1 = __builtin_amdgcn_cvt_pk_f32_fp8(uw[fn], true);
        sc[fn][0] = p0.x; sc[fn][1] = p0.y; sc[fn][2] = p1.x; sc[fn][3] = p1.y;
      }
    }
    __builtin_amdgcn_s_setprio(1);
#pragma unroll
    for (int kk = 0; kk < 2; kk++) {
      bf16x8 aq = kk == 0 ? aq0 : aq1;
#pragma unroll
      for (int fn = 0; fn < 4; fn++) {
        int row = fn * 16 + qr;
        int slot = (kk * 4 + hi) ^ (row & 7);
        bf16x8 bk = *(const bf16x8*)((const char*)&Ks[buf][0] + row * 128 +
                                     slot * 16);
        sc[fn] = __builtin_amdgcn_mfma_f32_16x16x32_bf16(bk, aq, sc[fn],
                                                         0, 0, 0);
      }
    }
    __builtin_amdgcn_s_setprio(0);
    // per-lane online softmax (base-2), defer-max threshold 8
    float pa = max3f(sc[0][0], sc[0][1], sc[0][2]);
    float pb = max3f(sc[0][3], sc[1][0], sc[1][1]);
    pa = max3f(pa, sc[1][2], sc[1][3]);
    pb = max3f(pb, sc[2][0], sc[2][1]);
    pa = max3f(pa, sc[2][2], sc[2][3]);
    pb = max3f(pb, sc[3][0], sc[3][1]);
    pa = max3f(pa, sc[3][2], sc[3][3]);
    float pm = fmaxf(pa, pb);
    pm = fmaxf(pm, __shfl_xor(pm, 16));
    pm = fmaxf(pm, __shfl_xor(pm, 32));
    if (__any(pm > m_ + 8.f)) {
      float mn = fmaxf(m_, pm);
      float f = exp2v(m_ - mn);
#pragma unroll
      for (int fn = 0; fn < 4; fn++)
#pragma unroll
        for (int r = 0; r < 4; r++) oa[fn][r] *= f;
#pragma unroll
      for (int r = 0; r < 4; r++) lacc[r] *= f;
      m_ = mn;
    }
#pragma unroll
    for (int fn = 0; fn < 4; fn++)
#pragma unroll
      for (int r = 0; r < 4; r++) sc[fn][r] = exp2v(sc[fn][r] - m_);
    // pack P (kv-contig per lane) -> per-wave swizzled LDS, 4x b64 writes
#pragma unroll
    for (int fn = 0; fn < 4; fn++) {
      unsigned w0 = cvtpk(sc[fn][0], sc[fn][1]);
      unsigned w1 = cvtpk(sc[fn][2], sc[fn][3]);
      *(uint2*)(pw + ((fn * 32 + hi * 8) ^ qs)) = make_uint2(w0, w1);
    }
    // PV: O^T += V^T x P^T; row-sum via ones-MFMA
    __builtin_amdgcn_s_setprio(1);
#pragma unroll
    for (int ck = 0; ck < 2; ck++) {
      bf16x8 pt = *(const bf16x8*)(pw + ((ck * 64 + hi * 16) ^ qs));
#pragma unroll
      for (int fn = 0; fn < 4; fn++) {
        int row = fn * 16 + qr;
        int slot = (ck * 4 + hi) ^ (row & 7);
        bf16x8 av = *(const bf16x8*)((const char*)&Vs[buf][0] + row * 128 +
                                     slot * 16);
        oa[fn] = __builtin_amdgcn_mfma_f32_16x16x32_bf16(av, pt, oa[fn],
                                                         0, 0, 0);
      }
      lacc = __builtin_amdgcn_mfma_f32_16x16x32_bf16(vones, pt, lacc, 0, 0, 0);
    }
    __builtin_amdgcn_s_setprio(0);
    bu = nb;
    __syncthreads();
  }
  // epilogue: normalize + packed 8B stores (d = fn*16 + hi*4 + 0..3)
  float inv = 1.0f / lacc[0];
  u16* cp = ctx + (size_t)(b * SS + q0 + w * 16 + qr) * DD + h * 64 + hi * 4;
#pragma unroll
  for (int fn = 0; fn < 4; fn++) {
    unsigned w0 = cvtpk(oa[fn][0] * inv, oa[fn][1] * inv);
    unsigned w1 = cvtpk(oa[fn][2] * inv, oa[fn][3] * inv);
    *(uint2*)(cp + fn * 16) = make_uint2(w0, w1);
  }
}

// --------------------------------------------------------------------------
// residual + LayerNorm: x bf16 (o-proj out), res fp32; one wave per row.
__global__ __launch_bounds__(256) void k_ln(const u16* __restrict__ x,
                                            const float* __restrict__ res,
                                            const float* __restrict__ g,
                                            const float* __restrict__ bta,
                                            float* __restrict__ ho,
                                            u16* __restrict__ hbo) {
  int w = threadIdx.x >> 6, l = threadIdx.x & 63;
  int row = blockIdx.x * 4 + w;
  const u16* xr = x + (size_t)row * DD;
  const float* rr = res + (size_t)row * DD;
  float v[12];
  float s = 0.f, s2 = 0.f;
#pragma unroll
  for (int j = 0; j < 3; j++) {
    int c = j * 256 + l * 4;
    uint2 xv = *(const uint2*)(xr + c);
    float4 rv = *(const float4*)(rr + c);
    float a0 = bf2f(xv.x & 0xffffu) + rv.x;
    float a1 = bf2f(xv.x >> 16) + rv.y;
    float a2 = bf2f(xv.y & 0xffffu) + rv.z;
    float a3 = bf2f(xv.y >> 16) + rv.w;
    v[j * 4 + 0] = a0; v[j * 4 + 1] = a1; v[j * 4 + 2] = a2; v[j * 4 + 3] = a3;
    s += (a0 + a1) + (a2 + a3);
    s2 += (a0 * a0 + a1 * a1) + (a2 * a2 + a3 * a3);
  }
#pragma unroll
  for (int m = 1; m < 64; m <<= 1) {
    s += __shfl_xor(s, m);
    s2 += __shfl_xor(s2, m);
  }
  float mean = s * (1.f / 768.f);
  float var = s2 * (1.f / 768.f) - mean * mean;
  float rstd = rsqrtf(var + 1e-12f);
#pragma unroll
  for (int j = 0; j < 3; j++) {
    int c = j * 256 + l * 4;
    float4 gv = *(const float4*)(g + c);
    float4 bv = *(const float4*)(bta + c);
    float y0 = (v[j * 4 + 0] - mean) * rstd * gv.x + bv.x;
    float y1 = (v[j * 4 + 1] - mean) * rstd * gv.y + bv.y;
    float y2 = (v[j * 4 + 2] - mean) * rstd * gv.z + bv.z;
    float y3 = (v[j * 4 + 3] - mean) * rstd * gv.w + bv.w;
    *(float4*)(ho + (size_t)row * DD + c) = make_float4(y0, y1, y2, y3);
    *(uint2*)(hbo + (size_t)row * DD + c) =
        make_uint2(cvtpk(y0, y1), cvtpk(y2, y3));
  }
}

// --------------------------------------------------------------------------
extern "C" void kernel_launch(void* const* d_in, const int* in_sizes, int n_in,
                              void* d_out, int out_size, void* d_ws,
                              size_t ws_size, hipStream_t stream) {
  const float* hid = (const float*)d_in[0];
  const unsigned char* msk = (const unsigned char*)d_in[1];
  const int* pos = (const int*)d_in[2];
  const int* bbx = (const int*)d_in[3];
  const float* qw = (const float*)d_in[4];
  const float* qbv = (const float*)d_in[5];
  const float* kw = (const float*)d_in[6];
  const float* kbv = (const float*)d_in[7];
  const float* vw = (const float*)d_in[8];
  const float* vbv = (const float*)d_in[9];
  const float* ow = (const float*)d_in[10];
  const float* obv = (const float*)d_in[11];
  const float* lng = (const float*)d_in[12];
  const float* lnb = (const float*)d_in[13];
  const float* wpb = (const float*)d_in[14];
  const float* wxb = (const float*)d_in[15];
  const float* wyb = (const float*)d_in[16];
  float* outp = (float*)d_out;

  // workspace carve (~201 MiB)
  char* p = (char*)d_ws;
  u8* bias = (u8*)p;     p += (size_t)100663296;  // [B,H,S,S] fp8, pre-blocked
  float* hbuf = (float*)p; p += 12582912;         // residual stream fp32
  u16* hb = (u16*)p;     p += 6291456;            // h in bf16
  u16* qo = (u16*)p;     p += 6291456;
  u16* ko = (u16*)p;     p += 6291456;
  u16* vtb = (u16*)p;    p += 6291456;            // V transposed [BH][64][S]
  u16* ctxb = (u16*)p;   p += 6291456;
  u16* wtb = (u16*)p;    p += (size_t)56623104;   // ALL layers wT bf16
  u16* att = qo;                                  // alias q (dead by O-GEMM)

  k_hb<<<dim3(3072), dim3(256), 0, stream>>>((const float4*)hid, (uint2*)hb,
                                             786432);
  k_bias<<<dim3(2048), dim3(256), 0, stream>>>(pos, bbx, msk, wpb, wxb, wyb,
                                               bias);
  k_wconv_all<<<dim3(6912), dim3(256), 0, stream>>>(qw, kw, vw, ow, wtb);
  for (int l = 0; l < NLAYER; l++) {
    const u16* wl = wtb + (size_t)l * WT_LSTRIDE;
    k_gemm_qkv<<<dim3(576), dim3(256), 0, stream>>>(
        hb, wl, qbv + l * DD, kbv + l * DD, vbv + l * DD, qo, ko, vtb);
    k_attn<<<dim3(768), dim3(256), 0, stream>>>(qo, ko, vtb, bias, ctxb);
    k_gemm_o<<<dim3(192), dim3(256), 0, stream>>>(
        ctxb, wl + (size_t)3 * DD * DD, obv + l * DD, att);
    k_ln<<<dim3(1024), dim3(256), 0, stream>>>(
        att, l == 0 ? hid : (const float*)hbuf, lng + l * DD, lnb + l * DD,
        l == 11 ? outp : hbuf, hb);
  }
}

// Round 14
// 1321.687 us; speedup vs baseline: 1.4752x; 1.0471x over previous
//
#include <hip/hip_runtime.h>

// ---------------------------------------------------------------------------
// ErnieLayout encoder, 12 layers, B=2 S=2048 D=768 H=12 DH=64, bf16 MFMA.
// r14 = r13 + attn: (1) 2-deep bias prefetch (bias slice is L3-resident,
// ~500cy — 1-deep wasn't covering it; 12MB/XCD working set >> 4MB L2),
// (2) lane-local defer-max trigger (row-max shfl×2 only in the rare
// rescale branch; __any does the wave reduction for free).
// ---------------------------------------------------------------------------

#define BB 2
#define SS 2048
#define DD 768
#define HH 12
#define NLAYER 12
#define MM 4096  // BB*SS

typedef unsigned short u16;
typedef unsigned char u8;
typedef __attribute__((ext_vector_type(8))) short bf16x8;
typedef __attribute__((ext_vector_type(4))) float f32x4;
typedef __attribute__((ext_vector_type(2))) float f32x2;

#define LOG2E 1.44269504088896340736f
#define WT_LSTRIDE 2359296  // per-layer u16 elements in wtb (4*768*768)

__device__ __forceinline__ u16 f2bf(float f) {
  unsigned u = __float_as_uint(f);
  unsigned r = (u + 0x7FFFu + ((u >> 16) & 1u)) >> 16;
  return (u16)r;
}
__device__ __forceinline__ float bf2f(unsigned u) {
  return __uint_as_float(u << 16);
}
__device__ __forceinline__ unsigned cvtpk(float a, float b) {
  unsigned r;
  asm("v_cvt_pk_bf16_f32 %0, %1, %2" : "=v"(r) : "v"(a), "v"(b));
  return r;
}
__device__ __forceinline__ float exp2v(float x) {
  float r;
  asm("v_exp_f32 %0, %1" : "=v"(r) : "v"(x));
  return r;
}
__device__ __forceinline__ float log2v(float x) {
  float r;
  asm("v_log_f32 %0, %1" : "=v"(r) : "v"(x));
  return r;
}
__device__ __forceinline__ float max3f(float a, float b, float c) {
  float r;
  asm("v_max3_f32 %0, %1, %2, %3" : "=v"(r) : "v"(a), "v"(b), "v"(c));
  return r;
}

__device__ __forceinline__ void g2lds16(const void* g, void* l) {
  __builtin_amdgcn_global_load_lds(
      (const __attribute__((address_space(1))) unsigned int*)g,
      (__attribute__((address_space(3))) unsigned int*)l, 16, 0, 0);
}

// --------------------------------------------------------------------------
// hidden fp32 -> bf16
__global__ __launch_bounds__(256) void k_hb(const float4* __restrict__ x,
                                            uint2* __restrict__ o, int n4) {
  int i = blockIdx.x * 256 + threadIdx.x;
  if (i < n4) {
    float4 v = x[i];
    uint2 r;
    r.x = (unsigned)f2bf(v.x) | ((unsigned)f2bf(v.y) << 16);
    r.y = (unsigned)f2bf(v.z) | ((unsigned)f2bf(v.w) << 16);
    o[i] = r;
  }
}

// --------------------------------------------------------------------------
// relative-position bucketing; hardware log2 (exact algebraic rewrite)
__device__ __forceinline__ int bucket1(int rel) {
  int ret = rel > 0 ? 16 : 0;
  int n = rel < 0 ? -rel : rel;
  if (n < 8) return ret + n;
  int v = 8 + (int)(log2v((float)n * 0.125f) * 2.0f);
  return ret + (v < 15 ? v : 15);
}
__device__ __forceinline__ int bucket2(int rel) {
  int ret = rel > 0 ? 32 : 0;
  int n = rel < 0 ? -rel : rel;
  if (n < 16) return ret + n;
  int v = 16 + (int)(log2v((float)n * 0.0625f) * 4.0f);
  return ret + (v < 31 ? v : 31);
}

// Bias precompute -> fp8 e4m3 table. Layout: [b][h][qt32][kt32][tid256][16]
// fp8 bytes, sub = fn*4+r with swapped-attn mapping (q-row = w*16+(l&15),
// kv = fn*16+(l>>4)*4+r). Values pre-scaled by log2(e); mask -> sat(-448).
__global__ __launch_bounds__(256) void k_bias(
    const int* __restrict__ pos, const int* __restrict__ bbx,
    const unsigned char* __restrict__ msk,
    const float* __restrict__ wp, const float* __restrict__ wx,
    const float* __restrict__ wy, u8* __restrict__ bias) {
  int bid = blockIdx.x;                 // b*1024 + qt*32 + kt
  int b = bid >> 10, qt = (bid >> 5) & 31, kt = bid & 31;
  __shared__ __align__(16) float swpT[3][32][4], swxT[3][64][4], swyT[3][64][4];
  __shared__ int pq[64], xq[64], yq[64], pk[64], xk[64], yk[64];
  __shared__ unsigned char mk[64];
  int t = threadIdx.x;
  for (int i = t; i < 384; i += 256) {
    int g = i >> 7, idx = i & 127;
    swpT[g][idx >> 2][idx & 3] = wp[(g * 4 + (idx & 3)) * 32 + (idx >> 2)] * LOG2E;
  }
  for (int i = t; i < 768; i += 256) {
    int g = i >> 8, idx = i & 255;
    swxT[g][idx >> 2][idx & 3] = wx[(g * 4 + (idx & 3)) * 64 + (idx >> 2)] * LOG2E;
    swyT[g][idx >> 2][idx & 3] = wy[(g * 4 + (idx & 3)) * 64 + (idx >> 2)] * LOG2E;
  }
  int q0 = qt * 64, k0 = kt * 64;
  if (t < 64) {
    int gi = b * SS + q0 + t;
    pq[t] = pos[gi]; xq[t] = bbx[gi * 4]; yq[t] = bbx[gi * 4 + 3];
  } else if (t < 128) {
    int j = t - 64, gi = b * SS + k0 + j;
    pk[j] = pos[gi]; xk[j] = bbx[gi * 4]; yk[j] = bbx[gi * 4 + 3];
    mk[j] = msk[b * SS + k0 + j];
  }
  __syncthreads();
  int w = t >> 6, l = t & 63;
  int hi = l >> 4;
  int qlr = w * 16 + (l & 15);
  int pql = pq[qlr], xql = xq[qlr], yql = yq[qlr];
  int packed[16];
#pragma unroll
  for (int fn = 0; fn < 4; fn++)
#pragma unroll
    for (int r = 0; r < 4; r++) {
      int kl = fn * 16 + hi * 4 + r;
      int b1 = bucket1(pk[kl] - pql);
      int b2 = bucket2(xk[kl] - xql);
      int b3 = bucket2(yk[kl] - yql);
      packed[fn * 4 + r] = b1 | (b2 << 5) | (b3 << 11) | (mk[kl] ? (1 << 17) : 0);
    }
  for (int hg = 0; hg < 3; hg++) {
    unsigned words[4][4];  // [head][word]
#pragma unroll
    for (int j2 = 0; j2 < 8; j2++) {
      float a0[4], a1[4];
      {
        int p = packed[2 * j2];
        f32x4 ap = *(const f32x4*)swpT[hg][p & 31];
        f32x4 bx = *(const f32x4*)swxT[hg][(p >> 5) & 63];
        f32x4 cy = *(const f32x4*)swyT[hg][(p >> 11) & 63];
        bool mm = (p >> 17) != 0;
#pragma unroll
        for (int hh = 0; hh < 4; hh++)
          a0[hh] = mm ? -3.0e38f : (ap[hh] + bx[hh] + cy[hh]);
      }
      {
        int p = packed[2 * j2 + 1];
        f32x4 ap = *(const f32x4*)swpT[hg][p & 31];
        f32x4 bx = *(const f32x4*)swxT[hg][(p >> 5) & 63];
        f32x4 cy = *(const f32x4*)swyT[hg][(p >> 11) & 63];
        bool mm = (p >> 17) != 0;
#pragma unroll
        for (int hh = 0; hh < 4; hh++)
          a1[hh] = mm ? -3.0e38f : (ap[hh] + bx[hh] + cy[hh]);
      }
      int wd = j2 >> 1;
      if ((j2 & 1) == 0) {
#pragma unroll
        for (int hh = 0; hh < 4; hh++)
          words[hh][wd] = __builtin_amdgcn_cvt_pk_fp8_f32(a0[hh], a1[hh], 0, false);
      } else {
#pragma unroll
        for (int hh = 0; hh < 4; hh++)
          words[hh][wd] = __builtin_amdgcn_cvt_pk_fp8_f32(a0[hh], a1[hh],
                                                          words[hh][wd], true);
      }
    }
#pragma unroll
    for (int hh = 0; hh < 4; hh++) {
      int h = hg * 4 + hh;
      u8* dst = bias +
          ((size_t)((b * 12 + h) * 1024 + qt * 32 + kt) * 256 + t) * 16;
      *(uint4*)dst = make_uint4(words[hh][0], words[hh][1], words[hh][2],
                                words[hh][3]);
    }
  }
}

// --------------------------------------------------------------------------
// ALL-layer weight convert fp32 -> bf16, transposed to [out][in], one launch
__global__ __launch_bounds__(256) void k_wconv_all(
    const float* __restrict__ qw, const float* __restrict__ kw,
    const float* __restrict__ vw, const float* __restrict__ ow,
    u16* __restrict__ wt) {
  int bid = blockIdx.x;                     // layer*576 + g*144 + nt*12 + kt
  int layer = bid / 576, rem = bid % 576;
  int g = rem / 144, rr_ = rem % 144, nt = rr_ / 12, kt = rr_ % 12;
  const float* src = g == 0 ? qw : g == 1 ? kw : g == 2 ? vw : ow;
  src += (size_t)layer * DD * DD;
  __shared__ float sm[64][67];
  int t = threadIdx.x, c2 = t & 31, r0 = t >> 5;
#pragma unroll
  for (int p = 0; p < 8; p++) {
    int row = r0 + p * 8;
    float2 v = *(const float2*)&src[(size_t)(kt * 64 + row) * DD + nt * 64 + c2 * 2];
    sm[row][c2 * 2] = v.x;
    sm[row][c2 * 2 + 1] = v.y;
  }
  __syncthreads();
  u16* dst = wt + (size_t)layer * WT_LSTRIDE + (size_t)g * DD * DD;
#pragma unroll
  for (int p = 0; p < 8; p++) {
    int n = r0 + p * 8;
    float v0 = sm[c2 * 2][n], v1 = sm[c2 * 2 + 1][n];
    *(unsigned*)&dst[(size_t)(nt * 64 + n) * DD + kt * 64 + c2 * 2] = cvtpk(v0, v1);
  }
}

// --------------------------------------------------------------------------
// GEMM core (2-phase): C[128,128] = A[128,768] x Bt[128,768]^T, BK=64,
// double-buffered XOR-swizzled LDS; STAGE(t+1) issued BEFORE compute(t);
// ONE __syncthreads per K-step.
__device__ __forceinline__ void gemm_core(const u16* __restrict__ A,
                                          const u16* __restrict__ Bt, u16* As,
                                          u16* Bs, f32x4 acc[4][4], int tid) {
  int w = tid >> 6, l = tid & 63;
  int wm = w >> 1, wn = w & 1;
#pragma unroll
  for (int i = 0; i < 4; i++)
#pragma unroll
    for (int j = 0; j < 4; j++) acc[i][j] = f32x4{0.f, 0.f, 0.f, 0.f};
  int r0 = w * 32;
  auto STG = [&](int kt, int buf) {
#pragma unroll
    for (int j = 0; j < 4; j++) {
      int row = r0 + j * 8 + (l >> 3);
      int sl = (l & 7) ^ (row & 7);
      g2lds16(A + (size_t)row * DD + kt * 64 + sl * 8,
              As + buf * 8192 + (r0 + j * 8) * 64);
      g2lds16(Bt + (size_t)row * DD + kt * 64 + sl * 8,
              Bs + buf * 8192 + (r0 + j * 8) * 64);
    }
  };
  STG(0, 0);
  __syncthreads();
  for (int kt = 0; kt < 12; kt++) {
    int buf = kt & 1;
    if (kt < 11) STG(kt + 1, buf ^ 1);
    const char* Ab = (const char*)(As + buf * 8192);
    const char* Bb = (const char*)(Bs + buf * 8192);
#pragma unroll
    for (int kk = 0; kk < 2; kk++) {
      bf16x8 af[4], bfr[4];
#pragma unroll
      for (int fm = 0; fm < 4; fm++) {
        int row = wm * 64 + fm * 16 + (l & 15);
        int slot = (kk * 4 + (l >> 4)) ^ (row & 7);
        af[fm] = *(const bf16x8*)(Ab + row * 128 + slot * 16);
      }
#pragma unroll
      for (int fn = 0; fn < 4; fn++) {
        int row = wn * 64 + fn * 16 + (l & 15);
        int slot = (kk * 4 + (l >> 4)) ^ (row & 7);
        bfr[fn] = *(const bf16x8*)(Bb + row * 128 + slot * 16);
      }
#pragma unroll
      for (int fm = 0; fm < 4; fm++)
#pragma unroll
        for (int fn = 0; fn < 4; fn++)
          acc[fm][fn] = __builtin_amdgcn_mfma_f32_16x16x32_bf16(
              af[fm], bfr[fn], acc[fm][fn], 0, 0, 0);
    }
    __syncthreads();
  }
}

// fused QKV GEMM (N = 3*768); q scaled by log2(e)/8; V written TRANSPOSED
__global__ __launch_bounds__(256) void k_gemm_qkv(
    const u16* __restrict__ hb, const u16* __restrict__ wt,
    const float* __restrict__ qbias, const float* __restrict__ kbias,
    const float* __restrict__ vbias, u16* __restrict__ qo, u16* __restrict__ ko,
    u16* __restrict__ vtb) {
  __shared__ __align__(16) u16 As[2 * 128 * 64];
  __shared__ __align__(16) u16 Bs[2 * 128 * 64];
  int bid0 = blockIdx.x;
  int bid = (bid0 & 7) * 72 + (bid0 >> 3);   // XCD chunk swizzle (576 = 8*72)
  int mblk = bid / 18, nblk = bid % 18;
  int g = nblk / 6, nb = nblk % 6;
  const u16* A = hb + (size_t)mblk * 128 * DD;
  const u16* Bt = wt + (size_t)g * DD * DD + (size_t)nb * 128 * DD;
  f32x4 acc[4][4];
  gemm_core(A, Bt, As, Bs, acc, threadIdx.x);
  int w = threadIdx.x >> 6, l = threadIdx.x & 63;
  int wm = w >> 1, wn = w & 1;
  int hi4 = (l >> 4) << 2;
  if (g == 2) {
    // V: write transposed [bh][d][s], packed 4-bf16 (s-contiguous) stores
#pragma unroll
    for (int fn = 0; fn < 4; fn++) {
      int col = nb * 128 + wn * 64 + fn * 16 + (l & 15);
      float bval = vbias[col];
      int h = col >> 6, d = col & 63;
#pragma unroll
      for (int fm = 0; fm < 4; fm++) {
        int row = mblk * 128 + wm * 64 + fm * 16 + hi4;
        int bb = row >> 11, s = row & 2047;
        unsigned p0 = cvtpk(acc[fm][fn][0] + bval, acc[fm][fn][1] + bval);
        unsigned p1 = cvtpk(acc[fm][fn][2] + bval, acc[fm][fn][3] + bval);
        *(uint2*)(vtb + ((size_t)(bb * 12 + h) * 64 + d) * 2048 + s) =
            make_uint2(p0, p1);
      }
    }
    return;
  }
  const float* bias = g == 0 ? qbias : kbias;
  u16* out = g == 0 ? qo : ko;
  float scale = g == 0 ? 0.125f * LOG2E : 1.0f;
#pragma unroll
  for (int fn = 0; fn < 4; fn++) {
    int col = nb * 128 + wn * 64 + fn * 16 + (l & 15);
    float bval = bias[col];
#pragma unroll
    for (int fm = 0; fm < 4; fm++)
#pragma unroll
      for (int r = 0; r < 4; r++) {
        int row = mblk * 128 + wm * 64 + fm * 16 + hi4 + r;
        out[(size_t)row * DD + col] = f2bf((acc[fm][fn][r] + bval) * scale);
      }
  }
}

// O-projection GEMM, bf16 output (residual+LN done in k_ln, fp32 residual)
__global__ __launch_bounds__(256) void k_gemm_o(const u16* __restrict__ ctx,
                                                const u16* __restrict__ wto,
                                                const float* __restrict__ obias,
                                                u16* __restrict__ outp) {
  __shared__ __align__(16) u16 As[2 * 128 * 64];
  __shared__ __align__(16) u16 Bs[2 * 128 * 64];
  int bid0 = blockIdx.x;
  int bid = (bid0 & 7) * 24 + (bid0 >> 3);   // XCD chunk swizzle (192 = 8*24)
  int mblk = bid / 6, nblk = bid % 6;
  const u16* A = ctx + (size_t)mblk * 128 * DD;
  const u16* Bt = wto + (size_t)nblk * 128 * DD;
  f32x4 acc[4][4];
  gemm_core(A, Bt, As, Bs, acc, threadIdx.x);
  int w = threadIdx.x >> 6, l = threadIdx.x & 63;
  int wm = w >> 1, wn = w & 1;
#pragma unroll
  for (int fn = 0; fn < 4; fn++) {
    int col = nblk * 128 + wn * 64 + fn * 16 + (l & 15);
    float bval = obias[col];
#pragma unroll
    for (int fm = 0; fm < 4; fm++)
#pragma unroll
      for (int r = 0; r < 4; r++) {
        int row = mblk * 128 + wm * 64 + fm * 16 + ((l >> 4) << 2) + r;
        outp[(size_t)row * DD + col] = f2bf(acc[fm][fn][r] + bval);
      }
  }
}

// --------------------------------------------------------------------------
// Flash attention: swapped operands; K,V double-buffered g2lds LDS; fp8 bias
// acc-init with 2-DEEP prefetch; ones-MFMA row-sum; lane-local defer-max
// trigger (shfl only in the rare rescale branch); setprio; XCD swizzle.
__global__ __launch_bounds__(256) void k_attn(
    const u16* __restrict__ qm, const u16* __restrict__ kmat,
    const u16* __restrict__ vt, const u8* __restrict__ bias,
    u16* __restrict__ ctx) {
  int bid0 = blockIdx.x;
  int bid = (bid0 & 7) * 96 + (bid0 >> 3);   // XCD chunk swizzle (768 = 8*96)
  int qt = bid & 31, bh = bid >> 5;
  int b = bh / 12, h = bh % 12;
  __shared__ __align__(16) u16 Ks[2][64 * 64];
  __shared__ __align__(16) u16 Vs[2][64 * 64];
  __shared__ __align__(16) u16 Ps[4][16 * 64];
  int tid = threadIdx.x, w = tid >> 6, l = tid & 63;
  int hi = l >> 4, qr = l & 15;
  int q0 = qt * 64;
  const u16* qp = qm + (size_t)(b * SS + q0 + w * 16 + qr) * DD + h * 64 +
                  hi * 8;
  bf16x8 aq0 = *(const bf16x8*)qp;
  bf16x8 aq1 = *(const bf16x8*)(qp + 32);
  const u16* kb_ = kmat + (size_t)(b * SS) * DD + h * 64;
  const u16* vb_ = vt + (size_t)bh * 64 * SS;
  const u8* bb_ = bias + ((size_t)(bh * 32 + qt) * 32 * 256 + tid) * 16;
  f32x4 oa[4];
#pragma unroll
  for (int fn = 0; fn < 4; fn++) oa[fn] = f32x4{0.f, 0.f, 0.f, 0.f};
  f32x4 lacc = f32x4{0.f, 0.f, 0.f, 0.f};
  float m_ = -3.0e38f;
  bf16x8 vones;
#pragma unroll
  for (int i = 0; i < 8; i++) vones[i] = (short)0x3F80;
  int srow = tid >> 3, sc8 = tid & 7;

  auto STAGE = [&](int kt, int buf) {
#pragma unroll
    for (int j = 0; j < 2; j++) {
      int rr = srow + j * 32;
      int sl = sc8 ^ (rr & 7);
      g2lds16(kb_ + (size_t)(kt * 64 + rr) * DD + sl * 8,
              &Ks[buf][tid * 8 + j * 2048]);
      g2lds16(vb_ + (size_t)rr * SS + kt * 64 + sl * 8,
              &Vs[buf][tid * 8 + j * 2048]);
    }
  };

  STAGE(0, 0);
  uint4 bu = ((const uint4*)bb_)[0];                  // B[0]
  uint4 n1 = *(const uint4*)(bb_ + 4096);             // B[1]
  uint4 n2 = n1;
  char* pw = (char*)&Ps[w][0] + qr * 128;
  int qs = (qr & 7) << 4;
  __syncthreads();

  for (int kt = 0; kt < 32; kt++) {
    int buf = kt & 1;
    if (kt < 31) STAGE(kt + 1, buf ^ 1);
    if (kt < 30) n2 = *(const uint4*)(bb_ + (size_t)(kt + 2) * 4096);
    // acc-init from fp8 bias (word fn holds subs fn*4..fn*4+3)
    f32x4 sc[4];
    {
      unsigned uw[4] = {bu.x, bu.y, bu.z, bu.w};
#pragma unroll
      for (int fn = 0; fn < 4; fn++) {
        f32x2 p0 = __builtin_amdgcn_cvt_pk_f32_fp8(uw[fn], false);
        f32x2 p1 = __builtin_amdgcn_cvt_pk_f32_fp8(uw[fn], true);
        sc[fn][0] = p0.x; sc[fn][1] = p0.y; sc[fn][2] = p1.x; sc[fn][3] = p1.y;
      }
    }
    __builtin_amdgcn_s_setprio(1);
#pragma unroll
    for (int kk = 0; kk < 2; kk++) {
      bf16x8 aq = kk == 0 ? aq0 : aq1;
#pragma unroll
      for (int fn = 0; fn < 4; fn++) {
        int row = fn * 16 + qr;
        int slot = (kk * 4 + hi) ^ (row & 7);
        bf16x8 bk = *(const bf16x8*)((const char*)&Ks[buf][0] + row * 128 +
                                     slot * 16);
        sc[fn] = __builtin_amdgcn_mfma_f32_16x16x32_bf16(bk, aq, sc[fn],
                                                         0, 0, 0);
      }
    }
    __builtin_amdgcn_s_setprio(0);
    // lane-local max; __any reduces across the wave (no shfl on common path)
    float pa = max3f(sc[0][0], sc[0][1], sc[0][2]);
    float pb = max3f(sc[0][3], sc[1][0], sc[1][1]);
    pa = max3f(pa, sc[1][2], sc[1][3]);
    pb = max3f(pb, sc[2][0], sc[2][1]);
    pa = max3f(pa, sc[2][2], sc[2][3]);
    pb = max3f(pb, sc[3][0], sc[3][1]);
    pa = max3f(pa, sc[3][2], sc[3][3]);
    float pl = fmaxf(pa, pb);
    if (__any(pl > m_ + 8.f)) {
      float pm = fmaxf(pl, __shfl_xor(pl, 16));
      pm = fmaxf(pm, __shfl_xor(pm, 32));
      float mn = fmaxf(m_, pm);
      float f = exp2v(m_ - mn);
#pragma unroll
      for (int fn = 0; fn < 4; fn++)
#pragma unroll
        for (int r = 0; r < 4; r++) oa[fn][r] *= f;
#pragma unroll
      for (int r = 0; r < 4; r++) lacc[r] *= f;
      m_ = mn;
    }
#pragma unroll
    for (int fn = 0; fn < 4; fn++)
#pragma unroll
      for (int r = 0; r < 4; r++) sc[fn][r] = exp2v(sc[fn][r] - m_);
    // pack P (kv-contig per lane) -> per-wave swizzled LDS, 4x b64 writes
#pragma unroll
    for (int fn = 0; fn < 4; fn++) {
      unsigned w0 = cvtpk(sc[fn][0], sc[fn][1]);
      unsigned w1 = cvtpk(sc[fn][2], sc[fn][3]);
      *(uint2*)(pw + ((fn * 32 + hi * 8) ^ qs)) = make_uint2(w0, w1);
    }
    // PV: O^T += V^T x P^T; row-sum via ones-MFMA
    __builtin_amdgcn_s_setprio(1);
#pragma unroll
    for (int ck = 0; ck < 2; ck++) {
      bf16x8 pt = *(const bf16x8*)(pw + ((ck * 64 + hi * 16) ^ qs));
#pragma unroll
      for (int fn = 0; fn < 4; fn++) {
        int row = fn * 16 + qr;
        int slot = (ck * 4 + hi) ^ (row & 7);
        bf16x8 av = *(const bf16x8*)((const char*)&Vs[buf][0] + row * 128 +
                                     slot * 16);
        oa[fn] = __builtin_amdgcn_mfma_f32_16x16x32_bf16(av, pt, oa[fn],
                                                         0, 0, 0);
      }
      lacc = __builtin_amdgcn_mfma_f32_16x16x32_bf16(vones, pt, lacc, 0, 0, 0);
    }
    __builtin_amdgcn_s_setprio(0);
    bu = n1;
    n1 = n2;
    __syncthreads();
  }
  // epilogue: normalize + packed 8B stores (d = fn*16 + hi*4 + 0..3)
  float inv = 1.0f / lacc[0];
  u16* cp = ctx + (size_t)(b * SS + q0 + w * 16 + qr) * DD + h * 64 + hi * 4;
#pragma unroll
  for (int fn = 0; fn < 4; fn++) {
    unsigned w0 = cvtpk(oa[fn][0] * inv, oa[fn][1] * inv);
    unsigned w1 = cvtpk(oa[fn][2] * inv, oa[fn][3] * inv);
    *(uint2*)(cp + fn * 16) = make_uint2(w0, w1);
  }
}

// --------------------------------------------------------------------------
// residual + LayerNorm: x bf16 (o-proj out), res fp32; one wave per row.
__global__ __launch_bounds__(256) void k_ln(const u16* __restrict__ x,
                                            const float* __restrict__ res,
                                            const float* __restrict__ g,
                                            const float* __restrict__ bta,
                                            float* __restrict__ ho,
                                            u16* __restrict__ hbo) {
  int w = threadIdx.x >> 6, l = threadIdx.x & 63;
  int row = blockIdx.x * 4 + w;
  const u16* xr = x + (size_t)row * DD;
  const float* rr = res + (size_t)row * DD;
  float v[12];
  float s = 0.f, s2 = 0.f;
#pragma unroll
  for (int j = 0; j < 3; j++) {
    int c = j * 256 + l * 4;
    uint2 xv = *(const uint2*)(xr + c);
    float4 rv = *(const float4*)(rr + c);
    float a0 = bf2f(xv.x & 0xffffu) + rv.x;
    float a1 = bf2f(xv.x >> 16) + rv.y;
    float a2 = bf2f(xv.y & 0xffffu) + rv.z;
    float a3 = bf2f(xv.y >> 16) + rv.w;
    v[j * 4 + 0] = a0; v[j * 4 + 1] = a1; v[j * 4 + 2] = a2; v[j * 4 + 3] = a3;
    s += (a0 + a1) + (a2 + a3);
    s2 += (a0 * a0 + a1 * a1) + (a2 * a2 + a3 * a3);
  }
#pragma unroll
  for (int m = 1; m < 64; m <<= 1) {
    s += __shfl_xor(s, m);
    s2 += __shfl_xor(s2, m);
  }
  float mean = s * (1.f / 768.f);
  float var = s2 * (1.f / 768.f) - mean * mean;
  float rstd = rsqrtf(var + 1e-12f);
#pragma unroll
  for (int j = 0; j < 3; j++) {
    int c = j * 256 + l * 4;
    float4 gv = *(const float4*)(g + c);
    float4 bv = *(const float4*)(bta + c);
    float y0 = (v[j * 4 + 0] - mean) * rstd * gv.x + bv.x;
    float y1 = (v[j * 4 + 1] - mean) * rstd * gv.y + bv.y;
    float y2 = (v[j * 4 + 2] - mean) * rstd * gv.z + bv.z;
    float y3 = (v[j * 4 + 3] - mean) * rstd * gv.w + bv.w;
    *(float4*)(ho + (size_t)row * DD + c) = make_float4(y0, y1, y2, y3);
    *(uint2*)(hbo + (size_t)row * DD + c) =
        make_uint2(cvtpk(y0, y1), cvtpk(y2, y3));
  }
}

// --------------------------------------------------------------------------
extern "C" void kernel_launch(void* const* d_in, const int* in_sizes, int n_in,
                              void* d_out, int out_size, void* d_ws,
                              size_t ws_size, hipStream_t stream) {
  const float* hid = (const float*)d_in[0];
  const unsigned char* msk = (const unsigned char*)d_in[1];
  const int* pos = (const int*)d_in[2];
  const int* bbx = (const int*)d_in[3];
  const float* qw = (const float*)d_in[4];
  const float* qbv = (const float*)d_in[5];
  const float* kw = (const float*)d_in[6];
  const float* kbv = (const float*)d_in[7];
  const float* vw = (const float*)d_in[8];
  const float* vbv = (const float*)d_in[9];
  const float* ow = (const float*)d_in[10];
  const float* obv = (const float*)d_in[11];
  const float* lng = (const float*)d_in[12];
  const float* lnb = (const float*)d_in[13];
  const float* wpb = (const float*)d_in[14];
  const float* wxb = (const float*)d_in[15];
  const float* wyb = (const float*)d_in[16];
  float* outp = (float*)d_out;

  // workspace carve (~201 MiB)
  char* p = (char*)d_ws;
  u8* bias = (u8*)p;     p += (size_t)100663296;  // [B,H,S,S] fp8, pre-blocked
  float* hbuf = (float*)p; p += 12582912;         // residual stream fp32
  u16* hb = (u16*)p;     p += 6291456;            // h in bf16
  u16* qo = (u16*)p;     p += 6291456;
  u16* ko = (u16*)p;     p += 6291456;
  u16* vtb = (u16*)p;    p += 6291456;            // V transposed [BH][64][S]
  u16* ctxb = (u16*)p;   p += 6291456;
  u16* wtb = (u16*)p;    p += (size_t)56623104;   // ALL layers wT bf16
  u16* att = qo;                                  // alias q (dead by O-GEMM)

  k_hb<<<dim3(3072), dim3(256), 0, stream>>>((const float4*)hid, (uint2*)hb,
                                             786432);
  k_bias<<<dim3(2048), dim3(256), 0, stream>>>(pos, bbx, msk, wpb, wxb, wyb,
                                               bias);
  k_wconv_all<<<dim3(6912), dim3(256), 0, stream>>>(qw, kw, vw, ow, wtb);
  for (int l = 0; l < NLAYER; l++) {
    const u16* wl = wtb + (size_t)l * WT_LSTRIDE;
    k_gemm_qkv<<<dim3(576), dim3(256), 0, stream>>>(
        hb, wl, qbv + l * DD, kbv + l * DD, vbv + l * DD, qo, ko, vtb);
    k_attn<<<dim3(768), dim3(256), 0, stream>>>(qo, ko, vtb, bias, ctxb);
    k_gemm_o<<<dim3(192), dim3(256), 0, stream>>>(
        ctxb, wl + (size_t)3 * DD * DD, obv + l * DD, att);
    k_ln<<<dim3(1024), dim3(256), 0, stream>>>(
        att, l == 0 ? hid : (const float*)hbuf, lng + l * DD, lnb + l * DD,
        l == 11 ? outp : hbuf, hb);
  }
}

// Round 15
// 1321.515 us; speedup vs baseline: 1.4754x; 1.0001x over previous
//
#include <hip/hip_runtime.h>

// ---------------------------------------------------------------------------
// ErnieLayout encoder, 12 layers, B=2 S=2048 D=768 H=12 DH=64, bf16 MFMA.
// r15 = r14 + attn bias staged via global_load_lds (rides the same covered
// STAGE/barrier pipeline as K/V; kills the exposed L3-latency VGPR load —
// r14's "2-deep" prefetch was drained to 1-deep by the per-tile barrier).
// ---------------------------------------------------------------------------

#define BB 2
#define SS 2048
#define DD 768
#define HH 12
#define NLAYER 12
#define MM 4096  // BB*SS

typedef unsigned short u16;
typedef unsigned char u8;
typedef __attribute__((ext_vector_type(8))) short bf16x8;
typedef __attribute__((ext_vector_type(4))) float f32x4;
typedef __attribute__((ext_vector_type(2))) float f32x2;

#define LOG2E 1.44269504088896340736f
#define WT_LSTRIDE 2359296  // per-layer u16 elements in wtb (4*768*768)

__device__ __forceinline__ u16 f2bf(float f) {
  unsigned u = __float_as_uint(f);
  unsigned r = (u + 0x7FFFu + ((u >> 16) & 1u)) >> 16;
  return (u16)r;
}
__device__ __forceinline__ float bf2f(unsigned u) {
  return __uint_as_float(u << 16);
}
__device__ __forceinline__ unsigned cvtpk(float a, float b) {
  unsigned r;
  asm("v_cvt_pk_bf16_f32 %0, %1, %2" : "=v"(r) : "v"(a), "v"(b));
  return r;
}
__device__ __forceinline__ float exp2v(float x) {
  float r;
  asm("v_exp_f32 %0, %1" : "=v"(r) : "v"(x));
  return r;
}
__device__ __forceinline__ float log2v(float x) {
  float r;
  asm("v_log_f32 %0, %1" : "=v"(r) : "v"(x));
  return r;
}
__device__ __forceinline__ float max3f(float a, float b, float c) {
  float r;
  asm("v_max3_f32 %0, %1, %2, %3" : "=v"(r) : "v"(a), "v"(b), "v"(c));
  return r;
}

__device__ __forceinline__ void g2lds16(const void* g, void* l) {
  __builtin_amdgcn_global_load_lds(
      (const __attribute__((address_space(1))) unsigned int*)g,
      (__attribute__((address_space(3))) unsigned int*)l, 16, 0, 0);
}

// --------------------------------------------------------------------------
// hidden fp32 -> bf16
__global__ __launch_bounds__(256) void k_hb(const float4* __restrict__ x,
                                            uint2* __restrict__ o, int n4) {
  int i = blockIdx.x * 256 + threadIdx.x;
  if (i < n4) {
    float4 v = x[i];
    uint2 r;
    r.x = (unsigned)f2bf(v.x) | ((unsigned)f2bf(v.y) << 16);
    r.y = (unsigned)f2bf(v.z) | ((unsigned)f2bf(v.w) << 16);
    o[i] = r;
  }
}

// --------------------------------------------------------------------------
// relative-position bucketing; hardware log2 (exact algebraic rewrite)
__device__ __forceinline__ int bucket1(int rel) {
  int ret = rel > 0 ? 16 : 0;
  int n = rel < 0 ? -rel : rel;
  if (n < 8) return ret + n;
  int v = 8 + (int)(log2v((float)n * 0.125f) * 2.0f);
  return ret + (v < 15 ? v : 15);
}
__device__ __forceinline__ int bucket2(int rel) {
  int ret = rel > 0 ? 32 : 0;
  int n = rel < 0 ? -rel : rel;
  if (n < 16) return ret + n;
  int v = 16 + (int)(log2v((float)n * 0.0625f) * 4.0f);
  return ret + (v < 31 ? v : 31);
}

// Bias precompute -> fp8 e4m3 table. Layout: [b][h][qt32][kt32][tid256][16]
// fp8 bytes, sub = fn*4+r with swapped-attn mapping (q-row = w*16+(l&15),
// kv = fn*16+(l>>4)*4+r). Values pre-scaled by log2(e); mask -> sat(-448).
__global__ __launch_bounds__(256) void k_bias(
    const int* __restrict__ pos, const int* __restrict__ bbx,
    const unsigned char* __restrict__ msk,
    const float* __restrict__ wp, const float* __restrict__ wx,
    const float* __restrict__ wy, u8* __restrict__ bias) {
  int bid = blockIdx.x;                 // b*1024 + qt*32 + kt
  int b = bid >> 10, qt = (bid >> 5) & 31, kt = bid & 31;
  __shared__ __align__(16) float swpT[3][32][4], swxT[3][64][4], swyT[3][64][4];
  __shared__ int pq[64], xq[64], yq[64], pk[64], xk[64], yk[64];
  __shared__ unsigned char mk[64];
  int t = threadIdx.x;
  for (int i = t; i < 384; i += 256) {
    int g = i >> 7, idx = i & 127;
    swpT[g][idx >> 2][idx & 3] = wp[(g * 4 + (idx & 3)) * 32 + (idx >> 2)] * LOG2E;
  }
  for (int i = t; i < 768; i += 256) {
    int g = i >> 8, idx = i & 255;
    swxT[g][idx >> 2][idx & 3] = wx[(g * 4 + (idx & 3)) * 64 + (idx >> 2)] * LOG2E;
    swyT[g][idx >> 2][idx & 3] = wy[(g * 4 + (idx & 3)) * 64 + (idx >> 2)] * LOG2E;
  }
  int q0 = qt * 64, k0 = kt * 64;
  if (t < 64) {
    int gi = b * SS + q0 + t;
    pq[t] = pos[gi]; xq[t] = bbx[gi * 4]; yq[t] = bbx[gi * 4 + 3];
  } else if (t < 128) {
    int j = t - 64, gi = b * SS + k0 + j;
    pk[j] = pos[gi]; xk[j] = bbx[gi * 4]; yk[j] = bbx[gi * 4 + 3];
    mk[j] = msk[b * SS + k0 + j];
  }
  __syncthreads();
  int w = t >> 6, l = t & 63;
  int hi = l >> 4;
  int qlr = w * 16 + (l & 15);
  int pql = pq[qlr], xql = xq[qlr], yql = yq[qlr];
  int packed[16];
#pragma unroll
  for (int fn = 0; fn < 4; fn++)
#pragma unroll
    for (int r = 0; r < 4; r++) {
      int kl = fn * 16 + hi * 4 + r;
      int b1 = bucket1(pk[kl] - pql);
      int b2 = bucket2(xk[kl] - xql);
      int b3 = bucket2(yk[kl] - yql);
      packed[fn * 4 + r] = b1 | (b2 << 5) | (b3 << 11) | (mk[kl] ? (1 << 17) : 0);
    }
  for (int hg = 0; hg < 3; hg++) {
    unsigned words[4][4];  // [head][word]
#pragma unroll
    for (int j2 = 0; j2 < 8; j2++) {
      float a0[4], a1[4];
      {
        int p = packed[2 * j2];
        f32x4 ap = *(const f32x4*)swpT[hg][p & 31];
        f32x4 bx = *(const f32x4*)swxT[hg][(p >> 5) & 63];
        f32x4 cy = *(const f32x4*)swyT[hg][(p >> 11) & 63];
        bool mm = (p >> 17) != 0;
#pragma unroll
        for (int hh = 0; hh < 4; hh++)
          a0[hh] = mm ? -3.0e38f : (ap[hh] + bx[hh] + cy[hh]);
      }
      {
        int p = packed[2 * j2 + 1];
        f32x4 ap = *(const f32x4*)swpT[hg][p & 31];
        f32x4 bx = *(const f32x4*)swxT[hg][(p >> 5) & 63];
        f32x4 cy = *(const f32x4*)swyT[hg][(p >> 11) & 63];
        bool mm = (p >> 17) != 0;
#pragma unroll
        for (int hh = 0; hh < 4; hh++)
          a1[hh] = mm ? -3.0e38f : (ap[hh] + bx[hh] + cy[hh]);
      }
      int wd = j2 >> 1;
      if ((j2 & 1) == 0) {
#pragma unroll
        for (int hh = 0; hh < 4; hh++)
          words[hh][wd] = __builtin_amdgcn_cvt_pk_fp8_f32(a0[hh], a1[hh], 0, false);
      } else {
#pragma unroll
        for (int hh = 0; hh < 4; hh++)
          words[hh][wd] = __builtin_amdgcn_cvt_pk_fp8_f32(a0[hh], a1[hh],
                                                          words[hh][wd], true);
      }
    }
#pragma unroll
    for (int hh = 0; hh < 4; hh++) {
      int h = hg * 4 + hh;
      u8* dst = bias +
          ((size_t)((b * 12 + h) * 1024 + qt * 32 + kt) * 256 + t) * 16;
      *(uint4*)dst = make_uint4(words[hh][0], words[hh][1], words[hh][2],
                                words[hh][3]);
    }
  }
}

// --------------------------------------------------------------------------
// ALL-layer weight convert fp32 -> bf16, transposed to [out][in], one launch
__global__ __launch_bounds__(256) void k_wconv_all(
    const float* __restrict__ qw, const float* __restrict__ kw,
    const float* __restrict__ vw, const float* __restrict__ ow,
    u16* __restrict__ wt) {
  int bid = blockIdx.x;                     // layer*576 + g*144 + nt*12 + kt
  int layer = bid / 576, rem = bid % 576;
  int g = rem / 144, rr_ = rem % 144, nt = rr_ / 12, kt = rr_ % 12;
  const float* src = g == 0 ? qw : g == 1 ? kw : g == 2 ? vw : ow;
  src += (size_t)layer * DD * DD;
  __shared__ float sm[64][67];
  int t = threadIdx.x, c2 = t & 31, r0 = t >> 5;
#pragma unroll
  for (int p = 0; p < 8; p++) {
    int row = r0 + p * 8;
    float2 v = *(const float2*)&src[(size_t)(kt * 64 + row) * DD + nt * 64 + c2 * 2];
    sm[row][c2 * 2] = v.x;
    sm[row][c2 * 2 + 1] = v.y;
  }
  __syncthreads();
  u16* dst = wt + (size_t)layer * WT_LSTRIDE + (size_t)g * DD * DD;
#pragma unroll
  for (int p = 0; p < 8; p++) {
    int n = r0 + p * 8;
    float v0 = sm[c2 * 2][n], v1 = sm[c2 * 2 + 1][n];
    *(unsigned*)&dst[(size_t)(nt * 64 + n) * DD + kt * 64 + c2 * 2] = cvtpk(v0, v1);
  }
}

// --------------------------------------------------------------------------
// GEMM core (2-phase): C[128,128] = A[128,768] x Bt[128,768]^T, BK=64,
// double-buffered XOR-swizzled LDS; STAGE(t+1) issued BEFORE compute(t);
// ONE __syncthreads per K-step.
__device__ __forceinline__ void gemm_core(const u16* __restrict__ A,
                                          const u16* __restrict__ Bt, u16* As,
                                          u16* Bs, f32x4 acc[4][4], int tid) {
  int w = tid >> 6, l = tid & 63;
  int wm = w >> 1, wn = w & 1;
#pragma unroll
  for (int i = 0; i < 4; i++)
#pragma unroll
    for (int j = 0; j < 4; j++) acc[i][j] = f32x4{0.f, 0.f, 0.f, 0.f};
  int r0 = w * 32;
  auto STG = [&](int kt, int buf) {
#pragma unroll
    for (int j = 0; j < 4; j++) {
      int row = r0 + j * 8 + (l >> 3);
      int sl = (l & 7) ^ (row & 7);
      g2lds16(A + (size_t)row * DD + kt * 64 + sl * 8,
              As + buf * 8192 + (r0 + j * 8) * 64);
      g2lds16(Bt + (size_t)row * DD + kt * 64 + sl * 8,
              Bs + buf * 8192 + (r0 + j * 8) * 64);
    }
  };
  STG(0, 0);
  __syncthreads();
  for (int kt = 0; kt < 12; kt++) {
    int buf = kt & 1;
    if (kt < 11) STG(kt + 1, buf ^ 1);
    const char* Ab = (const char*)(As + buf * 8192);
    const char* Bb = (const char*)(Bs + buf * 8192);
#pragma unroll
    for (int kk = 0; kk < 2; kk++) {
      bf16x8 af[4], bfr[4];
#pragma unroll
      for (int fm = 0; fm < 4; fm++) {
        int row = wm * 64 + fm * 16 + (l & 15);
        int slot = (kk * 4 + (l >> 4)) ^ (row & 7);
        af[fm] = *(const bf16x8*)(Ab + row * 128 + slot * 16);
      }
#pragma unroll
      for (int fn = 0; fn < 4; fn++) {
        int row = wn * 64 + fn * 16 + (l & 15);
        int slot = (kk * 4 + (l >> 4)) ^ (row & 7);
        bfr[fn] = *(const bf16x8*)(Bb + row * 128 + slot * 16);
      }
#pragma unroll
      for (int fm = 0; fm < 4; fm++)
#pragma unroll
        for (int fn = 0; fn < 4; fn++)
          acc[fm][fn] = __builtin_amdgcn_mfma_f32_16x16x32_bf16(
              af[fm], bfr[fn], acc[fm][fn], 0, 0, 0);
    }
    __syncthreads();
  }
}

// fused QKV GEMM (N = 3*768); q scaled by log2(e)/8; V written TRANSPOSED
__global__ __launch_bounds__(256) void k_gemm_qkv(
    const u16* __restrict__ hb, const u16* __restrict__ wt,
    const float* __restrict__ qbias, const float* __restrict__ kbias,
    const float* __restrict__ vbias, u16* __restrict__ qo, u16* __restrict__ ko,
    u16* __restrict__ vtb) {
  __shared__ __align__(16) u16 As[2 * 128 * 64];
  __shared__ __align__(16) u16 Bs[2 * 128 * 64];
  int bid0 = blockIdx.x;
  int bid = (bid0 & 7) * 72 + (bid0 >> 3);   // XCD chunk swizzle (576 = 8*72)
  int mblk = bid / 18, nblk = bid % 18;
  int g = nblk / 6, nb = nblk % 6;
  const u16* A = hb + (size_t)mblk * 128 * DD;
  const u16* Bt = wt + (size_t)g * DD * DD + (size_t)nb * 128 * DD;
  f32x4 acc[4][4];
  gemm_core(A, Bt, As, Bs, acc, threadIdx.x);
  int w = threadIdx.x >> 6, l = threadIdx.x & 63;
  int wm = w >> 1, wn = w & 1;
  int hi4 = (l >> 4) << 2;
  if (g == 2) {
    // V: write transposed [bh][d][s], packed 4-bf16 (s-contiguous) stores
#pragma unroll
    for (int fn = 0; fn < 4; fn++) {
      int col = nb * 128 + wn * 64 + fn * 16 + (l & 15);
      float bval = vbias[col];
      int h = col >> 6, d = col & 63;
#pragma unroll
      for (int fm = 0; fm < 4; fm++) {
        int row = mblk * 128 + wm * 64 + fm * 16 + hi4;
        int bb = row >> 11, s = row & 2047;
        unsigned p0 = cvtpk(acc[fm][fn][0] + bval, acc[fm][fn][1] + bval);
        unsigned p1 = cvtpk(acc[fm][fn][2] + bval, acc[fm][fn][3] + bval);
        *(uint2*)(vtb + ((size_t)(bb * 12 + h) * 64 + d) * 2048 + s) =
            make_uint2(p0, p1);
      }
    }
    return;
  }
  const float* bias = g == 0 ? qbias : kbias;
  u16* out = g == 0 ? qo : ko;
  float scale = g == 0 ? 0.125f * LOG2E : 1.0f;
#pragma unroll
  for (int fn = 0; fn < 4; fn++) {
    int col = nb * 128 + wn * 64 + fn * 16 + (l & 15);
    float bval = bias[col];
#pragma unroll
    for (int fm = 0; fm < 4; fm++)
#pragma unroll
      for (int r = 0; r < 4; r++) {
        int row = mblk * 128 + wm * 64 + fm * 16 + hi4 + r;
        out[(size_t)row * DD + col] = f2bf((acc[fm][fn][r] + bval) * scale);
      }
  }
}

// O-projection GEMM, bf16 output (residual+LN done in k_ln, fp32 residual)
__global__ __launch_bounds__(256) void k_gemm_o(const u16* __restrict__ ctx,
                                                const u16* __restrict__ wto,
                                                const float* __restrict__ obias,
                                                u16* __restrict__ outp) {
  __shared__ __align__(16) u16 As[2 * 128 * 64];
  __shared__ __align__(16) u16 Bs[2 * 128 * 64];
  int bid0 = blockIdx.x;
  int bid = (bid0 & 7) * 24 + (bid0 >> 3);   // XCD chunk swizzle (192 = 8*24)
  int mblk = bid / 6, nblk = bid % 6;
  const u16* A = ctx + (size_t)mblk * 128 * DD;
  const u16* Bt = wto + (size_t)nblk * 128 * DD;
  f32x4 acc[4][4];
  gemm_core(A, Bt, As, Bs, acc, threadIdx.x);
  int w = threadIdx.x >> 6, l = threadIdx.x & 63;
  int wm = w >> 1, wn = w & 1;
#pragma unroll
  for (int fn = 0; fn < 4; fn++) {
    int col = nblk * 128 + wn * 64 + fn * 16 + (l & 15);
    float bval = obias[col];
#pragma unroll
    for (int fm = 0; fm < 4; fm++)
#pragma unroll
      for (int r = 0; r < 4; r++) {
        int row = mblk * 128 + wm * 64 + fm * 16 + ((l >> 4) << 2) + r;
        outp[(size_t)row * DD + col] = f2bf(acc[fm][fn][r] + bval);
      }
  }
}

// --------------------------------------------------------------------------
// Flash attention: swapped operands; K,V,BIAS all double-buffered g2lds LDS
// (bias rides the same covered stage/barrier pipeline); fp8 bias acc-init;
// ones-MFMA row-sum; lane-local defer-max; setprio; XCD swizzle.
__global__ __launch_bounds__(256) void k_attn(
    const u16* __restrict__ qm, const u16* __restrict__ kmat,
    const u16* __restrict__ vt, const u8* __restrict__ bias,
    u16* __restrict__ ctx) {
  int bid0 = blockIdx.x;
  int bid = (bid0 & 7) * 96 + (bid0 >> 3);   // XCD chunk swizzle (768 = 8*96)
  int qt = bid & 31, bh = bid >> 5;
  int b = bh / 12, h = bh % 12;
  __shared__ __align__(16) u16 Ks[2][64 * 64];
  __shared__ __align__(16) u16 Vs[2][64 * 64];
  __shared__ __align__(16) u16 Bsh[2][2048];   // 4KB fp8 bias tile per buf
  __shared__ __align__(16) u16 Ps[4][16 * 64];
  int tid = threadIdx.x, w = tid >> 6, l = tid & 63;
  int hi = l >> 4, qr = l & 15;
  int q0 = qt * 64;
  const u16* qp = qm + (size_t)(b * SS + q0 + w * 16 + qr) * DD + h * 64 +
                  hi * 8;
  bf16x8 aq0 = *(const bf16x8*)qp;
  bf16x8 aq1 = *(const bf16x8*)(qp + 32);
  const u16* kb_ = kmat + (size_t)(b * SS) * DD + h * 64;
  const u16* vb_ = vt + (size_t)bh * 64 * SS;
  const u8* bb_ = bias + ((size_t)(bh * 32 + qt) * 32 * 256 + tid) * 16;
  f32x4 oa[4];
#pragma unroll
  for (int fn = 0; fn < 4; fn++) oa[fn] = f32x4{0.f, 0.f, 0.f, 0.f};
  f32x4 lacc = f32x4{0.f, 0.f, 0.f, 0.f};
  float m_ = -3.0e38f;
  bf16x8 vones;
#pragma unroll
  for (int i = 0; i < 8; i++) vones[i] = (short)0x3F80;
  int srow = tid >> 3, sc8 = tid & 7;

  auto STAGE = [&](int kt, int buf) {
#pragma unroll
    for (int j = 0; j < 2; j++) {
      int rr = srow + j * 32;
      int sl = sc8 ^ (rr & 7);
      g2lds16(kb_ + (size_t)(kt * 64 + rr) * DD + sl * 8,
              &Ks[buf][tid * 8 + j * 2048]);
      g2lds16(vb_ + (size_t)rr * SS + kt * 64 + sl * 8,
              &Vs[buf][tid * 8 + j * 2048]);
    }
    g2lds16(bb_ + (size_t)kt * 4096, &Bsh[buf][tid * 8]);
  };

  STAGE(0, 0);
  char* pw = (char*)&Ps[w][0] + qr * 128;
  int qs = (qr & 7) << 4;
  __syncthreads();

  for (int kt = 0; kt < 32; kt++) {
    int buf = kt & 1;
    if (kt < 31) STAGE(kt + 1, buf ^ 1);
    // bias from LDS (ds_read_b128, conflict-free lane-linear), acc-init
    uint4 bu = *(const uint4*)((const char*)&Bsh[buf][0] + tid * 16);
    f32x4 sc[4];
    {
      unsigned uw[4] = {bu.x, bu.y, bu.z, bu.w};
#pragma unroll
      for (int fn = 0; fn < 4; fn++) {
        f32x2 p0 = __builtin_amdgcn_cvt_pk_f32_fp8(uw[fn], false);
        f32x2 p1 = __builtin_amdgcn_cvt_pk_f32_fp8(uw[fn], true);
        sc[fn][0] = p0.x; sc[fn][1] = p0.y; sc[fn][2] = p1.x; sc[fn][3] = p1.y;
      }
    }
    __builtin_amdgcn_s_setprio(1);
#pragma unroll
    for (int kk = 0; kk < 2; kk++) {
      bf16x8 aq = kk == 0 ? aq0 : aq1;
#pragma unroll
      for (int fn = 0; fn < 4; fn++) {
        int row = fn * 16 + qr;
        int slot = (kk * 4 + hi) ^ (row & 7);
        bf16x8 bk = *(const bf16x8*)((const char*)&Ks[buf][0] + row * 128 +
                                     slot * 16);
        sc[fn] = __builtin_amdgcn_mfma_f32_16x16x32_bf16(bk, aq, sc[fn],
                                                         0, 0, 0);
      }
    }
    __builtin_amdgcn_s_setprio(0);
    // lane-local max; __any reduces across the wave (no shfl on common path)
    float pa = max3f(sc[0][0], sc[0][1], sc[0][2]);
    float pb = max3f(sc[0][3], sc[1][0], sc[1][1]);
    pa = max3f(pa, sc[1][2], sc[1][3]);
    pb = max3f(pb, sc[2][0], sc[2][1]);
    pa = max3f(pa, sc[2][2], sc[2][3]);
    pb = max3f(pb, sc[3][0], sc[3][1]);
    pa = max3f(pa, sc[3][2], sc[3][3]);
    float pl = fmaxf(pa, pb);
    if (__any(pl > m_ + 8.f)) {
      float pm = fmaxf(pl, __shfl_xor(pl, 16));
      pm = fmaxf(pm, __shfl_xor(pm, 32));
      float mn = fmaxf(m_, pm);
      float f = exp2v(m_ - mn);
#pragma unroll
      for (int fn = 0; fn < 4; fn++)
#pragma unroll
        for (int r = 0; r < 4; r++) oa[fn][r] *= f;
#pragma unroll
      for (int r = 0; r < 4; r++) lacc[r] *= f;
      m_ = mn;
    }
#pragma unroll
    for (int fn = 0; fn < 4; fn++)
#pragma unroll
      for (int r = 0; r < 4; r++) sc[fn][r] = exp2v(sc[fn][r] - m_);
    // pack P (kv-contig per lane) -> per-wave swizzled LDS, 4x b64 writes
#pragma unroll
    for (int fn = 0; fn < 4; fn++) {
      unsigned w0 = cvtpk(sc[fn][0], sc[fn][1]);
      unsigned w1 = cvtpk(sc[fn][2], sc[fn][3]);
      *(uint2*)(pw + ((fn * 32 + hi * 8) ^ qs)) = make_uint2(w0, w1);
    }
    // PV: O^T += V^T x P^T; row-sum via ones-MFMA
    __builtin_amdgcn_s_setprio(1);
#pragma unroll
    for (int ck = 0; ck < 2; ck++) {
      bf16x8 pt = *(const bf16x8*)(pw + ((ck * 64 + hi * 16) ^ qs));
#pragma unroll
      for (int fn = 0; fn < 4; fn++) {
        int row = fn * 16 + qr;
        int slot = (ck * 4 + hi) ^ (row & 7);
        bf16x8 av = *(const bf16x8*)((const char*)&Vs[buf][0] + row * 128 +
                                     slot * 16);
        oa[fn] = __builtin_amdgcn_mfma_f32_16x16x32_bf16(av, pt, oa[fn],
                                                         0, 0, 0);
      }
      lacc = __builtin_amdgcn_mfma_f32_16x16x32_bf16(vones, pt, lacc, 0, 0, 0);
    }
    __builtin_amdgcn_s_setprio(0);
    __syncthreads();
  }
  // epilogue: normalize + packed 8B stores (d = fn*16 + hi*4 + 0..3)
  float inv = 1.0f / lacc[0];
  u16* cp = ctx + (size_t)(b * SS + q0 + w * 16 + qr) * DD + h * 64 + hi * 4;
#pragma unroll
  for (int fn = 0; fn < 4; fn++) {
    unsigned w0 = cvtpk(oa[fn][0] * inv, oa[fn][1] * inv);
    unsigned w1 = cvtpk(oa[fn][2] * inv, oa[fn][3] * inv);
    *(uint2*)(cp + fn * 16) = make_uint2(w0, w1);
  }
}

// --------------------------------------------------------------------------
// residual + LayerNorm: x bf16 (o-proj out), res fp32; one wave per row.
__global__ __launch_bounds__(256) void k_ln(const u16* __restrict__ x,
                                            const float* __restrict__ res,
                                            const float* __restrict__ g,
                                            const float* __restrict__ bta,
                                            float* __restrict__ ho,
                                            u16* __restrict__ hbo) {
  int w = threadIdx.x >> 6, l = threadIdx.x & 63;
  int row = blockIdx.x * 4 + w;
  const u16* xr = x + (size_t)row * DD;
  const float* rr = res + (size_t)row * DD;
  float v[12];
  float s = 0.f, s2 = 0.f;
#pragma unroll
  for (int j = 0; j < 3; j++) {
    int c = j * 256 + l * 4;
    uint2 xv = *(const uint2*)(xr + c);
    float4 rv = *(const float4*)(rr + c);
    float a0 = bf2f(xv.x & 0xffffu) + rv.x;
    float a1 = bf2f(xv.x >> 16) + rv.y;
    float a2 = bf2f(xv.y & 0xffffu) + rv.z;
    float a3 = bf2f(xv.y >> 16) + rv.w;
    v[j * 4 + 0] = a0; v[j * 4 + 1] = a1; v[j * 4 + 2] = a2; v[j * 4 + 3] = a3;
    s += (a0 + a1) + (a2 + a3);
    s2 += (a0 * a0 + a1 * a1) + (a2 * a2 + a3 * a3);
  }
#pragma unroll
  for (int m = 1; m < 64; m <<= 1) {
    s += __shfl_xor(s, m);
    s2 += __shfl_xor(s2, m);
  }
  float mean = s * (1.f / 768.f);
  float var = s2 * (1.f / 768.f) - mean * mean;
  float rstd = rsqrtf(var + 1e-12f);
#pragma unroll
  for (int j = 0; j < 3; j++) {
    int c = j * 256 + l * 4;
    float4 gv = *(const float4*)(g + c);
    float4 bv = *(const float4*)(bta + c);
    float y0 = (v[j * 4 + 0] - mean) * rstd * gv.x + bv.x;
    float y1 = (v[j * 4 + 1] - mean) * rstd * gv.y + bv.y;
    float y2 = (v[j * 4 + 2] - mean) * rstd * gv.z + bv.z;
    float y3 = (v[j * 4 + 3] - mean) * rstd * gv.w + bv.w;
    *(float4*)(ho + (size_t)row * DD + c) = make_float4(y0, y1, y2, y3);
    *(uint2*)(hbo + (size_t)row * DD + c) =
        make_uint2(cvtpk(y0, y1), cvtpk(y2, y3));
  }
}

// --------------------------------------------------------------------------
extern "C" void kernel_launch(void* const* d_in, const int* in_sizes, int n_in,
                              void* d_out, int out_size, void* d_ws,
                              size_t ws_size, hipStream_t stream) {
  const float* hid = (const float*)d_in[0];
  const unsigned char* msk = (const unsigned char*)d_in[1];
  const int* pos = (const int*)d_in[2];
  const int* bbx = (const int*)d_in[3];
  const float* qw = (const float*)d_in[4];
  const float* qbv = (const float*)d_in[5];
  const float* kw = (const float*)d_in[6];
  const float* kbv = (const float*)d_in[7];
  const float* vw = (const float*)d_in[8];
  const float* vbv = (const float*)d_in[9];
  const float* ow = (const float*)d_in[10];
  const float* obv = (const float*)d_in[11];
  const float* lng = (const float*)d_in[12];
  const float* lnb = (const float*)d_in[13];
  const float* wpb = (const float*)d_in[14];
  const float* wxb = (const float*)d_in[15];
  const float* wyb = (const float*)d_in[16];
  float* outp = (float*)d_out;

  // workspace carve (~201 MiB)
  char* p = (char*)d_ws;
  u8* bias = (u8*)p;     p += (size_t)100663296;  // [B,H,S,S] fp8, pre-blocked
  float* hbuf = (float*)p; p += 12582912;         // residual stream fp32
  u16* hb = (u16*)p;     p += 6291456;            // h in bf16
  u16* qo = (u16*)p;     p += 6291456;
  u16* ko = (u16*)p;     p += 6291456;
  u16* vtb = (u16*)p;    p += 6291456;            // V transposed [BH][64][S]
  u16* ctxb = (u16*)p;   p += 6291456;
  u16* wtb = (u16*)p;    p += (size_t)56623104;   // ALL layers wT bf16
  u16* att = qo;                                  // alias q (dead by O-GEMM)

  k_hb<<<dim3(3072), dim3(256), 0, stream>>>((const float4*)hid, (uint2*)hb,
                                             786432);
  k_bias<<<dim3(2048), dim3(256), 0, stream>>>(pos, bbx, msk, wpb, wxb, wyb,
                                               bias);
  k_wconv_all<<<dim3(6912), dim3(256), 0, stream>>>(qw, kw, vw, ow, wtb);
  for (int l = 0; l < NLAYER; l++) {
    const u16* wl = wtb + (size_t)l * WT_LSTRIDE;
    k_gemm_qkv<<<dim3(576), dim3(256), 0, stream>>>(
        hb, wl, qbv + l * DD, kbv + l * DD, vbv + l * DD, qo, ko, vtb);
    k_attn<<<dim3(768), dim3(256), 0, stream>>>(qo, ko, vtb, bias, ctxb);
    k_gemm_o<<<dim3(192), dim3(256), 0, stream>>>(
        ctxb, wl + (size_t)3 * DD * DD, obv + l * DD, att);
    k_ln<<<dim3(1024), dim3(256), 0, stream>>>(
        att, l == 0 ? hid : (const float*)hbuf, lng + l * DD, lnb + l * DD,
        l == 11 ? outp : hbuf, hb);
  }
}